// Round 2
// baseline (2132.764 us; speedup 1.0000x reference)
//
#include <hip/hip_runtime.h>
#include <hip/hip_bf16.h>
#include <math.h>

#ifndef __has_builtin
#define __has_builtin(x) 0
#endif

typedef unsigned int uint;
typedef unsigned short ushort;
typedef _Float16 half2_t __attribute__((ext_vector_type(2)));

// Problem constants: B=64, T=512, V=30000, E=256, H=256, K=9. 4H = 1024.
//
// LSTM geometry (round 2): 256 threads/block, 4 waves, 1 wave/SIMD ->
// 512-reg budget per thread. Thread j owns hidden unit j: all 4 gate rows
// {i,f,g,o}. W_hh fp16 k-pair packed as uint4 {i,f,g,o} per k-pair:
//   96 k-pairs/thread in 96 named uint4 scalars = 384 VGPRs (fits: 384 +
//   ~50 working < 512 — residence by construction, no asm tricks), plus
//   32 k-pairs in LDS (128 KB).
// Round-1 lesson: at 512 threads the budget is 256 (2 waves/SIMD) and the
// need was 316 -> unavoidable scratch streaming (~3200 stall cyc/step);
// forcing AGPRs via asm just moved the spill (asm pins location only at
// the asm site). Geometry change removes the conflict instead.
#define WREG_UINTS (96 * 256 * 4)          // 98304 (same buffer size)
#define WLDS_UINTS (32 * 256 * 4)          // 32768 (128 KB)

__device__ __forceinline__ float sigm(float x) {
    return __fdividef(1.0f, 1.0f + __expf(-x));
}
__device__ __forceinline__ float tanh_fast(float x) {
    float sg = __fdividef(1.0f, 1.0f + __expf(-2.0f * x));
    return sg + sg - 1.0f;
}
__device__ __forceinline__ float dot2f(uint w, uint h, float acc) {
#if __has_builtin(__builtin_amdgcn_fdot2)
    return __builtin_amdgcn_fdot2(__builtin_bit_cast(half2_t, w),
                                  __builtin_bit_cast(half2_t, h), acc, false);
#else
    half2_t a = __builtin_bit_cast(half2_t, w);
    half2_t b = __builtin_bit_cast(half2_t, h);
    return acc + (float)a.x * (float)b.x + (float)a.y * (float)b.y;
#endif
}
__device__ __forceinline__ uint packh2(float a, float b) {
    ushort u0 = __builtin_bit_cast(ushort, (_Float16)a);
    ushort u1 = __builtin_bit_cast(ushort, (_Float16)b);
    return (uint)u0 | ((uint)u1 << 16);
}

// ---- preprocessor repetition ------------------------------------------------
#define R96(X) \
  X(0) X(1) X(2) X(3) X(4) X(5) X(6) X(7) \
  X(8) X(9) X(10) X(11) X(12) X(13) X(14) X(15) \
  X(16) X(17) X(18) X(19) X(20) X(21) X(22) X(23) \
  X(24) X(25) X(26) X(27) X(28) X(29) X(30) X(31) \
  X(32) X(33) X(34) X(35) X(36) X(37) X(38) X(39) \
  X(40) X(41) X(42) X(43) X(44) X(45) X(46) X(47) \
  X(48) X(49) X(50) X(51) X(52) X(53) X(54) X(55) \
  X(56) X(57) X(58) X(59) X(60) X(61) X(62) X(63) \
  X(64) X(65) X(66) X(67) X(68) X(69) X(70) X(71) \
  X(72) X(73) X(74) X(75) X(76) X(77) X(78) X(79) \
  X(80) X(81) X(82) X(83) X(84) X(85) X(86) X(87) \
  X(88) X(89) X(90) X(91) X(92) X(93) X(94) X(95)

#define R32(X) \
  X(0) X(1) X(2) X(3) X(4) X(5) X(6) X(7) \
  X(8) X(9) X(10) X(11) X(12) X(13) X(14) X(15) \
  X(16) X(17) X(18) X(19) X(20) X(21) X(22) X(23) \
  X(24) X(25) X(26) X(27) X(28) X(29) X(30) X(31)

// W k-pair m for thread j lives at wreg4[m*256 + j] = uint4 of the 4 gates'
// fp16 pairs. One readlane broadcast feeds 4 dot2s (vs 2 in the 512-thread
// layout). h pairs: 128 uints; lane l holds r0=pair(l), r1=pair(64+l).
// Pairs 0..63 -> r0 lane m; 64..95 -> r1 lane m-64; 96..127 (LDS) -> r1
// lane 32+i.
#define WDECL(m) uint4 wv##m;
#define WLOAD(m) wv##m = wreg4[((m) << 8) + tid];
#define WSTEP(m) { \
    uint hpv = (uint)__builtin_amdgcn_readlane((int)((m) < 64 ? r0 : r1), (m) & 63); \
    aI = dot2f(wv##m.x, hpv, aI); \
    aF = dot2f(wv##m.y, hpv, aF); \
    aG = dot2f(wv##m.z, hpv, aG); \
    aO = dot2f(wv##m.w, hpv, aO); }
#define LSTEP(i) { \
    uint4 w4 = lw[((i) << 8) + tid]; \
    uint hpv = (uint)__builtin_amdgcn_readlane((int)r1, 32 + (i)); \
    aI = dot2f(w4.x, hpv, aI); \
    aF = dot2f(w4.y, hpv, aF); \
    aG = dot2f(w4.z, hpv, aG); \
    aO = dot2f(w4.w, hpv, aO); }

// ---------------------------------------------------------------------------
// zero_kernel: zero loss, preds, and feats rows with t >= len (masked region).
// ---------------------------------------------------------------------------
__global__ __launch_bounds__(256) void zero_kernel(float* __restrict__ out,
                                                   const int* __restrict__ lens) {
    int bid = blockIdx.x;
    if (bid < 65536) {
        int g = bid * 256 + threadIdx.x;
        int row = g >> 9;
        int t = row & 511;
        int b = row >> 9;
        if (t >= lens[b]) out[32769 + g] = 0.0f;
    } else if (bid < 65536 + 128) {
        int p = (bid - 65536) * 256 + threadIdx.x;
        out[1 + p] = 0.0f;
    } else if (threadIdx.x == 0) {
        out[0] = 0.0f;
    }
}

// ---------------------------------------------------------------------------
// pack_kernel: W_hh (4H,H) fp32 -> fp16 k-pair-packed uint4-of-gates.
// Output element (uint) id2 in [0,131072) per dir:
//   q = id2&3 (gate), u4 = id2>>2, j = u4&255 (hidden), m = u4>>8 (k-pair).
//   m<96 -> wreg[(m*256+j)*4+q] ; m>=96 -> wlds[((m-96)*256+j)*4+q].
// W_hh row for (gate q, hidden j) = q*256+j; k elements 2m, 2m+1.
// grid = 1024 x 256 covers 2 dirs x 131072.
// ---------------------------------------------------------------------------
__global__ __launch_bounds__(256) void pack_kernel(const float* __restrict__ WF,
                                                   const float* __restrict__ WB,
                                                   uint* __restrict__ wregF,
                                                   uint* __restrict__ wregB,
                                                   uint* __restrict__ wldsF,
                                                   uint* __restrict__ wldsB) {
    int id = blockIdx.x * 256 + threadIdx.x;   // 0..262143
    const float* W = WF; uint* wr = wregF; uint* wl = wldsF;
    if (id >= 131072) { id -= 131072; W = WB; wr = wregB; wl = wldsB; }
    int q = id & 3;
    int u4 = id >> 2;                 // 0..32767
    int j = u4 & 255;
    int m = u4 >> 8;                  // 0..127
    const float* row = W + ((size_t)((q << 8) + j) << 8);
    uint pk = packh2(row[2 * m], row[2 * m + 1]);
    if (m < 96) wr[(((m) << 8) + j) * 4 + q] = pk;
    else        wl[((((m - 96)) << 8) + j) * 4 + q] = pk;
}

// ---------------------------------------------------------------------------
// wih_pack_kernel: Wih fp32 -> fp16 k-pair packed, indexed by interleaved
// output column: wih16[col*128 + p], perm(col) = (col&3)*256 + (col>>2).
// Physical col 4j+q = gate q of hidden j  ->  gx row delivers {i,f,g,o}_j
// as the uint2 at uint-index 2j. (Exactly what lstm_kernel consumes.)
// ---------------------------------------------------------------------------
__global__ __launch_bounds__(256) void wih_pack_kernel(const float* __restrict__ WihF,
                                                       const float* __restrict__ WihB,
                                                       uint* __restrict__ w16F,
                                                       uint* __restrict__ w16B) {
    int id = blockIdx.x * 256 + threadIdx.x;   // 0..262143
    const float* W = WihF; uint* dst = w16F;
    if (id >= 131072) { id -= 131072; W = WihB; dst = w16B; }
    int col = id >> 7;
    int p = id & 127;
    int perm = ((col & 3) << 8) + (col >> 2);
    const float* row = W + ((size_t)perm << 8);
    dst[(col << 7) + p] = packh2(row[2 * p], row[2 * p + 1]);
}

// ---------------------------------------------------------------------------
// gemm_gx: fp16-pair dot2 GEMM. gx_il[row][col] = emb[row].Wih[perm(col)] +
// bias[perm(col)]. 64x64 tile, 32 k per iter, 4x4/thread. Skips masked tiles.
// grid = (512, 16)
// ---------------------------------------------------------------------------
__global__ __launch_bounds__(256) void gemm_gx_kernel(const int* __restrict__ widx,
                                                      const int* __restrict__ lens,
                                                      const float* __restrict__ wvec,
                                                      const uint* __restrict__ wih16,
                                                      const float* __restrict__ bias,
                                                      _Float16* __restrict__ gx) {
    int row0 = blockIdx.x * 64;
    int b = row0 >> 9;
    int t0 = row0 & 511;
    if (t0 >= lens[b]) return;
    int n0 = blockIdx.y * 64;

    __shared__ __align__(16) uint As[16][68];
    __shared__ __align__(16) uint Bs[16][68];
    __shared__ int aoff[64];

    int tid = threadIdx.x;
    if (tid < 64) aoff[tid] = widx[row0 + tid] << 8;
    __syncthreads();

    float acc[4][4] = {};
    int tn = tid & 15, tm = tid >> 4;

    for (int k0p = 0; k0p < 128; k0p += 16) {
#pragma unroll
        for (int p = 0; p < 4; ++p) {
            int lin = p * 256 + tid;
            int kp = lin & 15, m = lin >> 4;
            const float2 av = *reinterpret_cast<const float2*>(
                &wvec[aoff[m] + ((k0p + kp) << 1)]);
            As[kp][m] = packh2(av.x, av.y);
            Bs[kp][m] = wih16[((n0 + m) << 7) + k0p + kp];
        }
        __syncthreads();
#pragma unroll
        for (int kp = 0; kp < 16; ++kp) {
            uint4 a4 = *reinterpret_cast<const uint4*>(&As[kp][tm * 4]);
            uint4 b4 = *reinterpret_cast<const uint4*>(&Bs[kp][tn * 4]);
            uint am[4] = {a4.x, a4.y, a4.z, a4.w};
            uint bn[4] = {b4.x, b4.y, b4.z, b4.w};
#pragma unroll
            for (int i = 0; i < 4; ++i)
#pragma unroll
                for (int j = 0; j < 4; ++j) acc[i][j] = dot2f(am[i], bn[j], acc[i][j]);
        }
        __syncthreads();
    }

#pragma unroll
    for (int i = 0; i < 4; ++i) {
        int row = row0 + tm * 4 + i;
        ushort u[4];
#pragma unroll
        for (int j = 0; j < 4; ++j) {
            int col = n0 + tn * 4 + j;
            int perm = ((col & 3) << 8) + (col >> 2);
            u[j] = __builtin_bit_cast(ushort, (_Float16)(acc[i][j] + bias[perm]));
        }
        uint2 st;
        st.x = (uint)u[0] | ((uint)u[1] << 16);
        st.y = (uint)u[2] | ((uint)u[3] << 16);
        *reinterpret_cast<uint2*>(&gx[row * 1024 + n0 + tn * 4]) = st;
    }
}

// ---------------------------------------------------------------------------
// lstm_kernel: one block per (b, dir); 256 threads, 4 waves, 1 wave/SIMD
// (132 KB LDS -> 1 block/CU anyway; waves_per_eu(1,1) -> 512-reg budget).
// Thread j owns hidden unit j: gate rows i,f,g,o. 96 W k-pairs in 96 uint4
// named scalars (384 VGPRs, resident), 32 k-pairs in LDS. h broadcast via
// v_readlane of r0/r1 (fp16-pair packed). No gate exchange needed.
// feats store after the barrier: drains at the NEXT barrier, a step away.
// ---------------------------------------------------------------------------
__global__ __launch_bounds__(256, 1) __attribute__((amdgpu_waves_per_eu(1, 1)))
void lstm_kernel(const _Float16* __restrict__ gx0,
                 const _Float16* __restrict__ gx1,
                 const uint* __restrict__ wreg0,
                 const uint* __restrict__ wreg1,
                 const uint* __restrict__ wlds0,
                 const uint* __restrict__ wlds1,
                 const int* __restrict__ lens,
                 float* __restrict__ feats) {
    int dir = blockIdx.x & 1;
    int b = blockIdx.x >> 1;
    // gx row = 1024 fp16 = 256 uint2; batch b starts at row b*512.
    const uint2* gx2 = reinterpret_cast<const uint2*>(dir ? gx1 : gx0) +
                       ((size_t)b << 17);
    const uint4* wreg4 = reinterpret_cast<const uint4*>(dir ? wreg1 : wreg0);
    const uint4* wlds4 = reinterpret_cast<const uint4*>(dir ? wlds1 : wlds0);
    int len = lens[b];
    int tid = threadIdx.x;        // == hidden unit j
    int lane = tid & 63;

    __shared__ __align__(16) uint4 lw[32 * 256];     // 128 KB LDS W chunk
    __shared__ __align__(16) uint hbuf[2][128];      // fp16-pair h, dbuf

    for (int i = tid; i < 32 * 256; i += 256) lw[i] = wlds4[i];

    R96(WDECL)            // uint4 wv0..wv95 — 384 VGPRs, resident
    R96(WLOAD)
    __syncthreads();

    float c = 0.0f;
    uint r0 = 0, r1 = 0;
    int pp = 0;

    int t0i = dir ? (len - 1) : 0;
    uint2 g = gx2[(size_t)t0i * 256 + tid];

    for (int tp = 0; tp < len; ++tp) {
        int t = dir ? (len - 1 - tp) : tp;
        int tnn = dir ? (len - 2 - tp) : (tp + 1);
        tnn = tnn < 0 ? 0 : (tnn >= len ? len - 1 : tnn);
        uint2 gnext = gx2[(size_t)tnn * 256 + tid];

        half2_t g01 = __builtin_bit_cast(half2_t, g.x);
        half2_t g23 = __builtin_bit_cast(half2_t, g.y);
        float aI = (float)g01.x;
        float aF = (float)g01.y;
        float aG = (float)g23.x;
        float aO = (float)g23.y;

        R96(WSTEP)        // k-pairs 0..95: W in VGPRs, h via readlane
        R32(LSTEP)        // k-pairs 96..127: W in LDS

        float iv = sigm(aI);
        float fv = sigm(aF);
        float gv = tanh_fast(aG);
        float ov = sigm(aO);
        c = fv * c + iv * gv;
        float h = ov * tanh_fast(c);

        reinterpret_cast<ushort*>(hbuf[pp])[tid] =
            __builtin_bit_cast(ushort, (_Float16)h);
        __syncthreads();
        // global store after the barrier: drains at the NEXT barrier
        feats[(size_t)(((b << 9) + t)) * 512 + (dir << 8) + tid] = h;
        r0 = hbuf[pp][lane];
        r1 = hbuf[pp][64 + lane];
        pp ^= 1;
        g = gnext;
    }
}

// ---------------------------------------------------------------------------
// emis_kernel: emissions[b,t,k] = feats[b,t,:] . W_out[k,:] + b_out[k]
// ---------------------------------------------------------------------------
__global__ __launch_bounds__(64) void emis_kernel(const float* __restrict__ feats,
                                                  const float* __restrict__ Wout,
                                                  const float* __restrict__ bout,
                                                  const int* __restrict__ lens,
                                                  float* __restrict__ emis) {
    int r = blockIdx.x;
    int b = r >> 9, t = r & 511;
    if (t >= lens[b]) return;
    int lane = threadIdx.x;
    const float* fr = feats + (size_t)r * 512;
    float f[8];
#pragma unroll
    for (int i = 0; i < 8; ++i) f[i] = fr[i * 64 + lane];
#pragma unroll
    for (int k = 0; k < 9; ++k) {
        float p = 0.0f;
#pragma unroll
        for (int i = 0; i < 8; ++i) p = fmaf(f[i], Wout[k * 512 + i * 64 + lane], p);
#pragma unroll
        for (int off = 32; off; off >>= 1) p += __shfl_down(p, off);
        if (lane == 0) emis[r * 9 + k] = p + bout[k];
    }
}

// ---------------------------------------------------------------------------
// crf_kernel: alpha recursion + viterbi + backtrace + numerator + loss.
// ---------------------------------------------------------------------------
__global__ __launch_bounds__(64) void crf_kernel(const float* __restrict__ emis,
                                                 const int* __restrict__ lens,
                                                 const int* __restrict__ labels,
                                                 const float* __restrict__ start_trans,
                                                 const float* __restrict__ end_trans,
                                                 const float* __restrict__ trans,
                                                 float* __restrict__ out) {
    int b = blockIdx.x;
    int len = lens[b];
    int lane = threadIdx.x;
    __shared__ float alpha[9], vit[9];
    __shared__ unsigned char hist[512 * 9];
    const float* eb = emis + b * 512 * 9;
    const int* lb = labels + b * 512;

    float tr[9];
    if (lane < 9) {
#pragma unroll
        for (int i = 0; i < 9; ++i) tr[i] = trans[i * 9 + lane];
        float s0 = start_trans[lane] + eb[lane];
        alpha[lane] = s0;
        vit[lane] = s0;
    }
    __syncthreads();

    for (int t = 1; t < len; ++t) {
        float na = 0.0f, nv = 0.0f;
        if (lane < 9) {
            float e = eb[t * 9 + lane];
            float a[9];
#pragma unroll
            for (int i = 0; i < 9; ++i) a[i] = alpha[i] + tr[i];
            float m = a[0];
#pragma unroll
            for (int i = 1; i < 9; ++i) m = fmaxf(m, a[i]);
            float s = 0.0f;
#pragma unroll
            for (int i = 0; i < 9; ++i) s += __expf(a[i] - m);
            na = m + __logf(s) + e;
            float bv = vit[0] + tr[0];
            int bi = 0;
#pragma unroll
            for (int i = 1; i < 9; ++i) {
                float x = vit[i] + tr[i];
                if (x > bv) { bv = x; bi = i; }
            }
            nv = bv + e;
            hist[t * 9 + lane] = (unsigned char)bi;
        }
        __syncthreads();
        if (lane < 9) { alpha[lane] = na; vit[lane] = nv; }
        __syncthreads();
    }

    float part = 0.0f;
    for (int t = 1 + lane; t < len; t += 64) {
        int yp = lb[t - 1], y = lb[t];
        part += trans[yp * 9 + y] + eb[t * 9 + y];
    }
#pragma unroll
    for (int off = 32; off; off >>= 1) part += __shfl_down(part, off);

    if (lane == 0) {
        int y0 = lb[0];
        float num = start_trans[y0] + eb[y0] + part + end_trans[lb[len - 1]];
        float m = alpha[0] + end_trans[0];
        for (int j = 1; j < 9; ++j) m = fmaxf(m, alpha[j] + end_trans[j]);
        float s = 0.0f;
        for (int j = 0; j < 9; ++j) s += __expf(alpha[j] + end_trans[j] - m);
        float denom = m + __logf(s);
        atomicAdd(out, (denom - num) * (1.0f / 64.0f));

        float bm = vit[0] + end_trans[0];
        int cur = 0;
        for (int j = 1; j < 9; ++j) {
            float x = vit[j] + end_trans[j];
            if (x > bm) { bm = x; cur = j; }
        }
        float* preds = out + 1 + b * 512;
        preds[len - 1] = (float)cur;
        for (int t = len - 1; t >= 1; --t) {
            cur = hist[t * 9 + cur];
            preds[t - 1] = (float)cur;
        }
    }
}

// ---------------------------------------------------------------------------
extern "C" void kernel_launch(void* const* d_in, const int* in_sizes, int n_in,
                              void* d_out, int out_size, void* d_ws, size_t ws_size,
                              hipStream_t stream) {
    const int* widx = (const int*)d_in[0];
    const int* lens = (const int*)d_in[1];
    const int* labels = (const int*)d_in[2];
    const float* wvec = (const float*)d_in[3];
    const float* WihF = (const float*)d_in[4];
    const float* WhhF = (const float*)d_in[5];
    const float* bF = (const float*)d_in[6];
    const float* WihB = (const float*)d_in[7];
    const float* WhhB = (const float*)d_in[8];
    const float* bB = (const float*)d_in[9];
    const float* Wout = (const float*)d_in[10];
    const float* bout = (const float*)d_in[11];
    const float* start_trans = (const float*)d_in[12];
    const float* end_trans = (const float*)d_in[13];
    const float* trans9 = (const float*)d_in[14];
    float* out = (float*)d_out;
    char* ws = (char*)d_ws;

    // workspace layout (bytes)
    _Float16* gxF = (_Float16*)(ws);                        // 67,108,864
    _Float16* gxB = (_Float16*)(ws + 67108864);             // 67,108,864
    uint* wregF   = (uint*)(ws + 134217728);                // 393,216
    uint* wregB   = (uint*)(ws + 134610944);                // 393,216
    uint* wldsF   = (uint*)(ws + 135004160);                // 131,072
    uint* wldsB   = (uint*)(ws + 135135232);                // 131,072
    // wih16F/B live only before lstm; emis written after lstm -> safe alias
    uint* wih16F  = (uint*)(ws + 135266304);                // 524,288
    uint* wih16B  = (uint*)(ws + 135790592);                // 524,288
    float* emis   = (float*)(ws + 135266304);               // 1,179,648 (alias)
    (void)in_sizes; (void)n_in; (void)out_size; (void)ws_size;

    float* feats = out + 1 + 32768;   // feats output region (B,T,512) fp32

    zero_kernel<<<65665, 256, 0, stream>>>(out, lens);
    pack_kernel<<<1024, 256, 0, stream>>>(WhhF, WhhB, wregF, wregB, wldsF, wldsB);
    wih_pack_kernel<<<1024, 256, 0, stream>>>(WihF, WihB, wih16F, wih16B);

    dim3 ggrid(512, 16);
    gemm_gx_kernel<<<ggrid, 256, 0, stream>>>(widx, lens, wvec, wih16F, bF, gxF);
    gemm_gx_kernel<<<ggrid, 256, 0, stream>>>(widx, lens, wvec, wih16B, bB, gxB);

    lstm_kernel<<<128, 256, 0, stream>>>(gxF, gxB, wregF, wregB, wldsF, wldsB, lens, feats);

    emis_kernel<<<32768, 64, 0, stream>>>(feats, Wout, bout, lens, emis);
    crf_kernel<<<64, 64, 0, stream>>>(emis, lens, labels, start_trans, end_trans, trans9, out);
}

// Round 3
// 1673.294 us; speedup vs baseline: 1.2746x; 1.2746x over previous
//
#include <hip/hip_runtime.h>
#include <hip/hip_bf16.h>
#include <math.h>

#ifndef __has_builtin
#define __has_builtin(x) 0
#endif

typedef unsigned int uint;
typedef unsigned short ushort;
typedef _Float16 half2_t __attribute__((ext_vector_type(2)));

// Problem constants: B=64, T=512, V=30000, E=256, H=256, K=9. 4H = 1024.
//
// LSTM residence ledger (learned over rounds 0-2):
//   - arch VGPRs cap at 256/thread (v0..v255) — 4-gate/thread (384 uints)
//     is impossible (round 2: VGPR_Count 212, 56 pairs scratch-spilled).
//   - forcing AGPRs via asm at 2 waves/EU busts the 256 unified budget
//     (round 1: 192 AGPR + 116 VGPR = 308 -> spill + pinned schedule).
//   - 512-thread / 2-gates-per-thread needs 192 W uints + ~30 working
//     = ~222 <= 256: the ONLY geometry that fits. Round 0 failed just
//     because the default allocator budget was ~116 (it ignores that
//     132 KB LDS already forces 1 block/CU = 2 waves/SIMD).
// This round: round-0 plain named scalars + amdgpu_waves_per_eu(2,2) to
// raise the allocator budget to 256. No asm.
#define PREG 96
#define WREG_UINTS (PREG * 2 * 512)        // 98304
#define WLDS_UINTS (16 * 512 * 4)          // 32768 (16 uint4-groups)

__device__ __forceinline__ float sigm(float x) {
    return __fdividef(1.0f, 1.0f + __expf(-x));
}
__device__ __forceinline__ float tanh_fast(float x) {
    float sg = __fdividef(1.0f, 1.0f + __expf(-2.0f * x));
    return sg + sg - 1.0f;
}
__device__ __forceinline__ float dot2f(uint w, uint h, float acc) {
#if __has_builtin(__builtin_amdgcn_fdot2)
    return __builtin_amdgcn_fdot2(__builtin_bit_cast(half2_t, w),
                                  __builtin_bit_cast(half2_t, h), acc, false);
#else
    half2_t a = __builtin_bit_cast(half2_t, w);
    half2_t b = __builtin_bit_cast(half2_t, h);
    return acc + (float)a.x * (float)b.x + (float)a.y * (float)b.y;
#endif
}
__device__ __forceinline__ uint packh2(float a, float b) {
    ushort u0 = __builtin_bit_cast(ushort, (_Float16)a);
    ushort u1 = __builtin_bit_cast(ushort, (_Float16)b);
    return (uint)u0 | ((uint)u1 << 16);
}

// ---- preprocessor repetition ------------------------------------------------
#define R96(X) \
  X(0) X(1) X(2) X(3) X(4) X(5) X(6) X(7) \
  X(8) X(9) X(10) X(11) X(12) X(13) X(14) X(15) \
  X(16) X(17) X(18) X(19) X(20) X(21) X(22) X(23) \
  X(24) X(25) X(26) X(27) X(28) X(29) X(30) X(31) \
  X(32) X(33) X(34) X(35) X(36) X(37) X(38) X(39) \
  X(40) X(41) X(42) X(43) X(44) X(45) X(46) X(47) \
  X(48) X(49) X(50) X(51) X(52) X(53) X(54) X(55) \
  X(56) X(57) X(58) X(59) X(60) X(61) X(62) X(63) \
  X(64) X(65) X(66) X(67) X(68) X(69) X(70) X(71) \
  X(72) X(73) X(74) X(75) X(76) X(77) X(78) X(79) \
  X(80) X(81) X(82) X(83) X(84) X(85) X(86) X(87) \
  X(88) X(89) X(90) X(91) X(92) X(93) X(94) X(95)

#define R16(X) \
  X(0) X(1) X(2) X(3) X(4) X(5) X(6) X(7) \
  X(8) X(9) X(10) X(11) X(12) X(13) X(14) X(15)

// W k-pairs as 192 NAMED SCALAR uints -> plain VGPRs. With the 256-reg
// budget (waves_per_eu(2,2)) the whole set + ~30 working regs fits; SSA
// scalars cannot become allocas, so no scratch.
#define WDECL(m) uint wA##m, wB##m;
#define WLOAD(m) wA##m = wreg[(2 * (m)) * 512 + tid]; \
                 wB##m = wreg[(2 * (m) + 1) * 512 + tid];
#define WSTEP(m) { \
    uint hp = (uint)__builtin_amdgcn_readlane((int)((m) < 64 ? r0 : r1), (m) & 63); \
    aA = dot2f(wA##m, hp, aA); \
    aB = dot2f(wB##m, hp, aB); }
#define LSTEP(i) { \
    uint4 w4 = reinterpret_cast<const uint4*>(lw)[((i) << 9) + tid]; \
    uint hp0 = (uint)__builtin_amdgcn_readlane((int)r1, 32 + 2 * (i)); \
    uint hp1 = (uint)__builtin_amdgcn_readlane((int)r1, 33 + 2 * (i)); \
    aA = dot2f(w4.x, hp0, aA); \
    aB = dot2f(w4.y, hp0, aB); \
    aA = dot2f(w4.z, hp1, aA); \
    aB = dot2f(w4.w, hp1, aB); }

// ---------------------------------------------------------------------------
// zero_kernel: zero loss, preds, and feats rows with t >= len (masked region).
// ---------------------------------------------------------------------------
__global__ __launch_bounds__(256) void zero_kernel(float* __restrict__ out,
                                                   const int* __restrict__ lens) {
    int bid = blockIdx.x;
    if (bid < 65536) {
        int g = bid * 256 + threadIdx.x;
        int row = g >> 9;
        int t = row & 511;
        int b = row >> 9;
        if (t >= lens[b]) out[32769 + g] = 0.0f;
    } else if (bid < 65536 + 128) {
        int p = (bid - 65536) * 256 + threadIdx.x;
        out[1 + p] = 0.0f;
    } else if (threadIdx.x == 0) {
        out[0] = 0.0f;
    }
}

// ---------------------------------------------------------------------------
// pack_kernel: W_hh (4H,H) fp32 -> fp16 k-pair-packed. Thread tl=2j+s owns
// gates q=2s+x. Scalar chunk (m<96): wreg[(m*2+x)*512+tl]. LDS chunk
// (m=96..127): flat id2 = ((g*512+tl)*4 + c), m=96+2g+(c>>1), x=c&1.
// Per-direction ids: 98304 + 32768 = 131072. grid = 1024 x 256.
// ---------------------------------------------------------------------------
__global__ __launch_bounds__(256) void pack_kernel(const float* __restrict__ WF,
                                                   const float* __restrict__ WB,
                                                   uint* __restrict__ wregF,
                                                   uint* __restrict__ wregB,
                                                   uint* __restrict__ wldsF,
                                                   uint* __restrict__ wldsB) {
    int id = blockIdx.x * 256 + threadIdx.x;   // 0..262143
    const float* W = WF; uint* wr = wregF; uint* wl = wldsF;
    if (id >= 131072) { id -= 131072; W = WB; wr = wregB; wl = wldsB; }
    int m, x, tl, dst_lds = 0, id2 = 0;
    if (id < WREG_UINTS) {
        m = id >> 10;
        int r = id & 1023;
        x = r >> 9;
        tl = r & 511;
    } else {
        id2 = id - WREG_UINTS;            // 0..32767
        int c = id2 & 3;
        int u = id2 >> 2;
        tl = u & 511;
        int g = u >> 9;                   // 0..15
        m = PREG + 2 * g + (c >> 1);
        x = c & 1;
        dst_lds = 1;
    }
    int j = tl >> 1, s = tl & 1;
    int q = (s << 1) + x;
    const float* row = W + ((size_t)((q << 8) + j) << 8);
    uint pk = packh2(row[2 * m], row[2 * m + 1]);
    if (dst_lds) wl[id2] = pk;
    else         wr[((m << 1) + x) * 512 + tl] = pk;
}

// ---------------------------------------------------------------------------
// wih_pack_kernel: Wih fp32 -> fp16 k-pair packed, indexed by interleaved
// output column: wih16[col*128 + p], perm(col) = (col&3)*256 + (col>>2).
// ---------------------------------------------------------------------------
__global__ __launch_bounds__(256) void wih_pack_kernel(const float* __restrict__ WihF,
                                                       const float* __restrict__ WihB,
                                                       uint* __restrict__ w16F,
                                                       uint* __restrict__ w16B) {
    int id = blockIdx.x * 256 + threadIdx.x;   // 0..262143
    const float* W = WihF; uint* dst = w16F;
    if (id >= 131072) { id -= 131072; W = WihB; dst = w16B; }
    int col = id >> 7;
    int p = id & 127;
    int perm = ((col & 3) << 8) + (col >> 2);
    const float* row = W + ((size_t)perm << 8);
    dst[(col << 7) + p] = packh2(row[2 * p], row[2 * p + 1]);
}

// ---------------------------------------------------------------------------
// gemm_gx: fp16-pair dot2 GEMM. gx_il[row][col] = emb[row].Wih[perm(col)] +
// bias[perm(col)]. 64x64 tile, 32 k per iter, 4x4/thread. Skips masked tiles.
// grid = (512, 16)
// ---------------------------------------------------------------------------
__global__ __launch_bounds__(256) void gemm_gx_kernel(const int* __restrict__ widx,
                                                      const int* __restrict__ lens,
                                                      const float* __restrict__ wvec,
                                                      const uint* __restrict__ wih16,
                                                      const float* __restrict__ bias,
                                                      _Float16* __restrict__ gx) {
    int row0 = blockIdx.x * 64;
    int b = row0 >> 9;
    int t0 = row0 & 511;
    if (t0 >= lens[b]) return;
    int n0 = blockIdx.y * 64;

    __shared__ __align__(16) uint As[16][68];
    __shared__ __align__(16) uint Bs[16][68];
    __shared__ int aoff[64];

    int tid = threadIdx.x;
    if (tid < 64) aoff[tid] = widx[row0 + tid] << 8;
    __syncthreads();

    float acc[4][4] = {};
    int tn = tid & 15, tm = tid >> 4;

    for (int k0p = 0; k0p < 128; k0p += 16) {
#pragma unroll
        for (int p = 0; p < 4; ++p) {
            int lin = p * 256 + tid;
            int kp = lin & 15, m = lin >> 4;
            const float2 av = *reinterpret_cast<const float2*>(
                &wvec[aoff[m] + ((k0p + kp) << 1)]);
            As[kp][m] = packh2(av.x, av.y);
            Bs[kp][m] = wih16[((n0 + m) << 7) + k0p + kp];
        }
        __syncthreads();
#pragma unroll
        for (int kp = 0; kp < 16; ++kp) {
            uint4 a4 = *reinterpret_cast<const uint4*>(&As[kp][tm * 4]);
            uint4 b4 = *reinterpret_cast<const uint4*>(&Bs[kp][tn * 4]);
            uint am[4] = {a4.x, a4.y, a4.z, a4.w};
            uint bn[4] = {b4.x, b4.y, b4.z, b4.w};
#pragma unroll
            for (int i = 0; i < 4; ++i)
#pragma unroll
                for (int j = 0; j < 4; ++j) acc[i][j] = dot2f(am[i], bn[j], acc[i][j]);
        }
        __syncthreads();
    }

#pragma unroll
    for (int i = 0; i < 4; ++i) {
        int row = row0 + tm * 4 + i;
        ushort u[4];
#pragma unroll
        for (int j = 0; j < 4; ++j) {
            int col = n0 + tn * 4 + j;
            int perm = ((col & 3) << 8) + (col >> 2);
            u[j] = __builtin_bit_cast(ushort, (_Float16)(acc[i][j] + bias[perm]));
        }
        uint2 st;
        st.x = (uint)u[0] | ((uint)u[1] << 16);
        st.y = (uint)u[2] | ((uint)u[3] << 16);
        *reinterpret_cast<uint2*>(&gx[row * 1024 + n0 + tn * 4]) = st;
    }
}

// ---------------------------------------------------------------------------
// lstm_kernel: one block per (b, dir); 512 threads. Thread 2j+s owns gate
// rows {2s, 2s+1} of hidden j. W_hh fp16 resident: 96 k-pairs/gate as 192
// NAMED SCALAR uints in plain VGPRs + 32 k-pairs in LDS (128 KB).
// waves_per_eu(2,2): 132 KB LDS forces 1 block/CU = 2 waves/SIMD anyway;
// telling the allocator raises its VGPR budget 116 -> 256 so the full W
// set (~222 regs incl. working set) is resident. No asm — round 1 showed
// asm-forced AGPRs bust the unified budget (192a+116v=308>256) and pin the
// schedule. h broadcast via v_readlane; gate halves via __shfl_xor; feats
// store after the barrier (drains a full step later).
// ---------------------------------------------------------------------------
__global__ __launch_bounds__(512) __attribute__((amdgpu_waves_per_eu(2, 2)))
void lstm_kernel(const _Float16* __restrict__ gx0,
                 const _Float16* __restrict__ gx1,
                 const uint* __restrict__ wreg0,
                 const uint* __restrict__ wreg1,
                 const uint* __restrict__ wlds0,
                 const uint* __restrict__ wlds1,
                 const int* __restrict__ lens,
                 float* __restrict__ feats) {
    int dir = blockIdx.x & 1;
    int b = blockIdx.x >> 1;
    const uint* gxu = reinterpret_cast<const uint*>(dir ? gx1 : gx0) + ((size_t)(b << 9) << 9);
    const uint* wreg = dir ? wreg1 : wreg0;
    const uint* wlds = dir ? wlds1 : wlds0;
    int len = lens[b];
    int tid = threadIdx.x;
    int lane = tid & 63;
    int sg = tid & 1;

    __shared__ __align__(16) uint lw[WLDS_UINTS];    // 128 KB LDS W chunk
    __shared__ __align__(16) uint hpair[2][128];     // fp16-pair h, dbuf

    for (int i = tid; i < WLDS_UINTS; i += 512) lw[i] = wlds[i];

    R96(WDECL)            // uint wA0..wA95, wB0..wB95 — named scalars
    R96(WLOAD)
    __syncthreads();

    float c = 0.0f;
    uint r0 = 0, r1 = 0;
    int pp = 0;

    int t0i = dir ? (len - 1) : 0;
    uint g = gxu[(t0i << 9) + tid];

    for (int tp = 0; tp < len; ++tp) {
        int t = dir ? (len - 1 - tp) : tp;
        int tnn = dir ? (len - 2 - tp) : (tp + 1);
        tnn = tnn < 0 ? 0 : (tnn >= len ? len - 1 : tnn);
        uint gnext = gxu[(tnn << 9) + tid];

        half2_t gv = __builtin_bit_cast(half2_t, g);
        float aA = (float)gv.x;
        float aB = (float)gv.y;

        R96(WSTEP)        // k-pairs 0..95: W in VGPRs, h via readlane
        R16(LSTEP)        // k-pairs 96..127: W in LDS

        // s=0: pA=sigm(i), pB=sigm(f) ; s=1: pA=tanh(g), pB=sigm(o)
        float y = sg ? aA + aA : aA;
        float sgm = __fdividef(1.0f, 1.0f + __expf(-y));
        float pA = sg ? sgm + sgm - 1.0f : sgm;
        float pB = sigm(aB);

        float oA = __shfl_xor(pA, 1);
        float oB = __shfl_xor(pB, 1);
        float si = sg ? oA : pA;
        float sf = sg ? oB : pB;
        float tg = sg ? pA : oA;
        float so = sg ? pB : oB;

        c = sf * c + si * tg;
        float h = so * tanh_fast(c);

        if (!sg) {
            reinterpret_cast<ushort*>(hpair[pp])[tid >> 1] =
                __builtin_bit_cast(ushort, (_Float16)h);
        }
        __syncthreads();
        // global store after the barrier: drains at the NEXT barrier
        if (!sg) {
            feats[(size_t)(((b << 9) + t)) * 512 + (dir << 8) + (tid >> 1)] = h;
        }
        r0 = hpair[pp][lane];
        r1 = hpair[pp][64 + lane];
        pp ^= 1;
        g = gnext;
    }
}

// ---------------------------------------------------------------------------
// emis_kernel: emissions[b,t,k] = feats[b,t,:] . W_out[k,:] + b_out[k]
// ---------------------------------------------------------------------------
__global__ __launch_bounds__(64) void emis_kernel(const float* __restrict__ feats,
                                                  const float* __restrict__ Wout,
                                                  const float* __restrict__ bout,
                                                  const int* __restrict__ lens,
                                                  float* __restrict__ emis) {
    int r = blockIdx.x;
    int b = r >> 9, t = r & 511;
    if (t >= lens[b]) return;
    int lane = threadIdx.x;
    const float* fr = feats + (size_t)r * 512;
    float f[8];
#pragma unroll
    for (int i = 0; i < 8; ++i) f[i] = fr[i * 64 + lane];
#pragma unroll
    for (int k = 0; k < 9; ++k) {
        float p = 0.0f;
#pragma unroll
        for (int i = 0; i < 8; ++i) p = fmaf(f[i], Wout[k * 512 + i * 64 + lane], p);
#pragma unroll
        for (int off = 32; off; off >>= 1) p += __shfl_down(p, off);
        if (lane == 0) emis[r * 9 + k] = p + bout[k];
    }
}

// ---------------------------------------------------------------------------
// crf_kernel: alpha recursion + viterbi + backtrace + numerator + loss.
// ---------------------------------------------------------------------------
__global__ __launch_bounds__(64) void crf_kernel(const float* __restrict__ emis,
                                                 const int* __restrict__ lens,
                                                 const int* __restrict__ labels,
                                                 const float* __restrict__ start_trans,
                                                 const float* __restrict__ end_trans,
                                                 const float* __restrict__ trans,
                                                 float* __restrict__ out) {
    int b = blockIdx.x;
    int len = lens[b];
    int lane = threadIdx.x;
    __shared__ float alpha[9], vit[9];
    __shared__ unsigned char hist[512 * 9];
    const float* eb = emis + b * 512 * 9;
    const int* lb = labels + b * 512;

    float tr[9];
    if (lane < 9) {
#pragma unroll
        for (int i = 0; i < 9; ++i) tr[i] = trans[i * 9 + lane];
        float s0 = start_trans[lane] + eb[lane];
        alpha[lane] = s0;
        vit[lane] = s0;
    }
    __syncthreads();

    for (int t = 1; t < len; ++t) {
        float na = 0.0f, nv = 0.0f;
        if (lane < 9) {
            float e = eb[t * 9 + lane];
            float a[9];
#pragma unroll
            for (int i = 0; i < 9; ++i) a[i] = alpha[i] + tr[i];
            float m = a[0];
#pragma unroll
            for (int i = 1; i < 9; ++i) m = fmaxf(m, a[i]);
            float s = 0.0f;
#pragma unroll
            for (int i = 0; i < 9; ++i) s += __expf(a[i] - m);
            na = m + __logf(s) + e;
            float bv = vit[0] + tr[0];
            int bi = 0;
#pragma unroll
            for (int i = 1; i < 9; ++i) {
                float x = vit[i] + tr[i];
                if (x > bv) { bv = x; bi = i; }
            }
            nv = bv + e;
            hist[t * 9 + lane] = (unsigned char)bi;
        }
        __syncthreads();
        if (lane < 9) { alpha[lane] = na; vit[lane] = nv; }
        __syncthreads();
    }

    float part = 0.0f;
    for (int t = 1 + lane; t < len; t += 64) {
        int yp = lb[t - 1], y = lb[t];
        part += trans[yp * 9 + y] + eb[t * 9 + y];
    }
#pragma unroll
    for (int off = 32; off; off >>= 1) part += __shfl_down(part, off);

    if (lane == 0) {
        int y0 = lb[0];
        float num = start_trans[y0] + eb[y0] + part + end_trans[lb[len - 1]];
        float m = alpha[0] + end_trans[0];
        for (int j = 1; j < 9; ++j) m = fmaxf(m, alpha[j] + end_trans[j]);
        float s = 0.0f;
        for (int j = 0; j < 9; ++j) s += __expf(alpha[j] + end_trans[j] - m);
        float denom = m + __logf(s);
        atomicAdd(out, (denom - num) * (1.0f / 64.0f));

        float bm = vit[0] + end_trans[0];
        int cur = 0;
        for (int j = 1; j < 9; ++j) {
            float x = vit[j] + end_trans[j];
            if (x > bm) { bm = x; cur = j; }
        }
        float* preds = out + 1 + b * 512;
        preds[len - 1] = (float)cur;
        for (int t = len - 1; t >= 1; --t) {
            cur = hist[t * 9 + cur];
            preds[t - 1] = (float)cur;
        }
    }
}

// ---------------------------------------------------------------------------
extern "C" void kernel_launch(void* const* d_in, const int* in_sizes, int n_in,
                              void* d_out, int out_size, void* d_ws, size_t ws_size,
                              hipStream_t stream) {
    const int* widx = (const int*)d_in[0];
    const int* lens = (const int*)d_in[1];
    const int* labels = (const int*)d_in[2];
    const float* wvec = (const float*)d_in[3];
    const float* WihF = (const float*)d_in[4];
    const float* WhhF = (const float*)d_in[5];
    const float* bF = (const float*)d_in[6];
    const float* WihB = (const float*)d_in[7];
    const float* WhhB = (const float*)d_in[8];
    const float* bB = (const float*)d_in[9];
    const float* Wout = (const float*)d_in[10];
    const float* bout = (const float*)d_in[11];
    const float* start_trans = (const float*)d_in[12];
    const float* end_trans = (const float*)d_in[13];
    const float* trans9 = (const float*)d_in[14];
    float* out = (float*)d_out;
    char* ws = (char*)d_ws;

    // workspace layout (bytes)
    _Float16* gxF = (_Float16*)(ws);                        // 67,108,864
    _Float16* gxB = (_Float16*)(ws + 67108864);             // 67,108,864
    uint* wregF   = (uint*)(ws + 134217728);                // 393,216
    uint* wregB   = (uint*)(ws + 134610944);                // 393,216
    uint* wldsF   = (uint*)(ws + 135004160);                // 131,072
    uint* wldsB   = (uint*)(ws + 135135232);                // 131,072
    // wih16F/B live only before lstm; emis written after lstm -> safe alias
    uint* wih16F  = (uint*)(ws + 135266304);                // 524,288
    uint* wih16B  = (uint*)(ws + 135790592);                // 524,288
    float* emis   = (float*)(ws + 135266304);               // 1,179,648 (alias)
    (void)in_sizes; (void)n_in; (void)out_size; (void)ws_size;

    float* feats = out + 1 + 32768;   // feats output region (B,T,512) fp32

    zero_kernel<<<65665, 256, 0, stream>>>(out, lens);
    pack_kernel<<<1024, 256, 0, stream>>>(WhhF, WhhB, wregF, wregB, wldsF, wldsB);
    wih_pack_kernel<<<1024, 256, 0, stream>>>(WihF, WihB, wih16F, wih16B);

    dim3 ggrid(512, 16);
    gemm_gx_kernel<<<ggrid, 256, 0, stream>>>(widx, lens, wvec, wih16F, bF, gxF);
    gemm_gx_kernel<<<ggrid, 256, 0, stream>>>(widx, lens, wvec, wih16B, bB, gxB);

    lstm_kernel<<<128, 512, 0, stream>>>(gxF, gxB, wregF, wregB, wldsF, wldsB, lens, feats);

    emis_kernel<<<32768, 64, 0, stream>>>(feats, Wout, bout, lens, emis);
    crf_kernel<<<64, 64, 0, stream>>>(emis, lens, labels, start_trans, end_trans, trans9, out);
}

// Round 4
// 1665.356 us; speedup vs baseline: 1.2807x; 1.0048x over previous
//
#include <hip/hip_runtime.h>
#include <hip/hip_bf16.h>
#include <math.h>

#ifndef __has_builtin
#define __has_builtin(x) 0
#endif

typedef unsigned int uint;
typedef unsigned short ushort;
typedef _Float16 half2_t __attribute__((ext_vector_type(2)));

// Problem constants: B=64, T=512, V=30000, E=256, H=256, K=9. 4H = 1024.
//
// LSTM residence ledger (rounds 0-3):
//   - arch VGPRs cap at 256/thread -> 4-gate/thread (384 uints) impossible
//     (round 2: VGPR_Count 212 + spill).
//   - asm-forced AGPRs at 512 threads bust the 256 unified budget
//     (round 1: 192a + 116v = 308 -> spill + pinned schedule).
//   - 512-thread / 2-gate layout needs 192 W + ~30 working = ~222 <= 256:
//     the only geometry that fits.
//   - THE BUDGET MECHANISM: backend does NOT fold LDS occupancy into its
//     register target; default = ~128 regs (4 waves/EU). The bare
//     amdgpu_waves_per_eu attribute is IGNORED (round 3: VGPR 116,
//     identical to round 0). The TWO-ARG __launch_bounds__ IS honored
//     (round 2: VGPR 212 with __launch_bounds__(256,1)).
// This round: round-0 kernel + __launch_bounds__(512, 2) -> budget 256.
#define PREG 96
#define WREG_UINTS (PREG * 2 * 512)        // 98304
#define WLDS_UINTS (16 * 512 * 4)          // 32768 (16 uint4-groups)

__device__ __forceinline__ float sigm(float x) {
    return __fdividef(1.0f, 1.0f + __expf(-x));
}
__device__ __forceinline__ float tanh_fast(float x) {
    float sg = __fdividef(1.0f, 1.0f + __expf(-2.0f * x));
    return sg + sg - 1.0f;
}
__device__ __forceinline__ float dot2f(uint w, uint h, float acc) {
#if __has_builtin(__builtin_amdgcn_fdot2)
    return __builtin_amdgcn_fdot2(__builtin_bit_cast(half2_t, w),
                                  __builtin_bit_cast(half2_t, h), acc, false);
#else
    half2_t a = __builtin_bit_cast(half2_t, w);
    half2_t b = __builtin_bit_cast(half2_t, h);
    return acc + (float)a.x * (float)b.x + (float)a.y * (float)b.y;
#endif
}
__device__ __forceinline__ uint packh2(float a, float b) {
    ushort u0 = __builtin_bit_cast(ushort, (_Float16)a);
    ushort u1 = __builtin_bit_cast(ushort, (_Float16)b);
    return (uint)u0 | ((uint)u1 << 16);
}

// ---- preprocessor repetition ------------------------------------------------
#define R96(X) \
  X(0) X(1) X(2) X(3) X(4) X(5) X(6) X(7) \
  X(8) X(9) X(10) X(11) X(12) X(13) X(14) X(15) \
  X(16) X(17) X(18) X(19) X(20) X(21) X(22) X(23) \
  X(24) X(25) X(26) X(27) X(28) X(29) X(30) X(31) \
  X(32) X(33) X(34) X(35) X(36) X(37) X(38) X(39) \
  X(40) X(41) X(42) X(43) X(44) X(45) X(46) X(47) \
  X(48) X(49) X(50) X(51) X(52) X(53) X(54) X(55) \
  X(56) X(57) X(58) X(59) X(60) X(61) X(62) X(63) \
  X(64) X(65) X(66) X(67) X(68) X(69) X(70) X(71) \
  X(72) X(73) X(74) X(75) X(76) X(77) X(78) X(79) \
  X(80) X(81) X(82) X(83) X(84) X(85) X(86) X(87) \
  X(88) X(89) X(90) X(91) X(92) X(93) X(94) X(95)

#define R16(X) \
  X(0) X(1) X(2) X(3) X(4) X(5) X(6) X(7) \
  X(8) X(9) X(10) X(11) X(12) X(13) X(14) X(15)

// W k-pairs as 192 NAMED SCALAR uints -> plain VGPRs. With the 256-reg
// budget (launch_bounds(512,2)) the whole set + ~30 working regs fits; SSA
// scalars cannot become allocas, so no scratch.
#define WDECL(m) uint wA##m, wB##m;
#define WLOAD(m) wA##m = wreg[(2 * (m)) * 512 + tid]; \
                 wB##m = wreg[(2 * (m) + 1) * 512 + tid];
#define WSTEP(m) { \
    uint hp = (uint)__builtin_amdgcn_readlane((int)((m) < 64 ? r0 : r1), (m) & 63); \
    aA = dot2f(wA##m, hp, aA); \
    aB = dot2f(wB##m, hp, aB); }
#define LSTEP(i) { \
    uint4 w4 = reinterpret_cast<const uint4*>(lw)[((i) << 9) + tid]; \
    uint hp0 = (uint)__builtin_amdgcn_readlane((int)r1, 32 + 2 * (i)); \
    uint hp1 = (uint)__builtin_amdgcn_readlane((int)r1, 33 + 2 * (i)); \
    aA = dot2f(w4.x, hp0, aA); \
    aB = dot2f(w4.y, hp0, aB); \
    aA = dot2f(w4.z, hp1, aA); \
    aB = dot2f(w4.w, hp1, aB); }

// ---------------------------------------------------------------------------
// zero_kernel: zero loss, preds, and feats rows with t >= len (masked region).
// ---------------------------------------------------------------------------
__global__ __launch_bounds__(256) void zero_kernel(float* __restrict__ out,
                                                   const int* __restrict__ lens) {
    int bid = blockIdx.x;
    if (bid < 65536) {
        int g = bid * 256 + threadIdx.x;
        int row = g >> 9;
        int t = row & 511;
        int b = row >> 9;
        if (t >= lens[b]) out[32769 + g] = 0.0f;
    } else if (bid < 65536 + 128) {
        int p = (bid - 65536) * 256 + threadIdx.x;
        out[1 + p] = 0.0f;
    } else if (threadIdx.x == 0) {
        out[0] = 0.0f;
    }
}

// ---------------------------------------------------------------------------
// pack_kernel: W_hh (4H,H) fp32 -> fp16 k-pair-packed. Thread tl=2j+s owns
// gates q=2s+x. Scalar chunk (m<96): wreg[(m*2+x)*512+tl]. LDS chunk
// (m=96..127): flat id2 = ((g*512+tl)*4 + c), m=96+2g+(c>>1), x=c&1.
// Per-direction ids: 98304 + 32768 = 131072. grid = 1024 x 256.
// ---------------------------------------------------------------------------
__global__ __launch_bounds__(256) void pack_kernel(const float* __restrict__ WF,
                                                   const float* __restrict__ WB,
                                                   uint* __restrict__ wregF,
                                                   uint* __restrict__ wregB,
                                                   uint* __restrict__ wldsF,
                                                   uint* __restrict__ wldsB) {
    int id = blockIdx.x * 256 + threadIdx.x;   // 0..262143
    const float* W = WF; uint* wr = wregF; uint* wl = wldsF;
    if (id >= 131072) { id -= 131072; W = WB; wr = wregB; wl = wldsB; }
    int m, x, tl, dst_lds = 0, id2 = 0;
    if (id < WREG_UINTS) {
        m = id >> 10;
        int r = id & 1023;
        x = r >> 9;
        tl = r & 511;
    } else {
        id2 = id - WREG_UINTS;            // 0..32767
        int c = id2 & 3;
        int u = id2 >> 2;
        tl = u & 511;
        int g = u >> 9;                   // 0..15
        m = PREG + 2 * g + (c >> 1);
        x = c & 1;
        dst_lds = 1;
    }
    int j = tl >> 1, s = tl & 1;
    int q = (s << 1) + x;
    const float* row = W + ((size_t)((q << 8) + j) << 8);
    uint pk = packh2(row[2 * m], row[2 * m + 1]);
    if (dst_lds) wl[id2] = pk;
    else         wr[((m << 1) + x) * 512 + tl] = pk;
}

// ---------------------------------------------------------------------------
// wih_pack_kernel: Wih fp32 -> fp16 k-pair packed, indexed by interleaved
// output column: wih16[col*128 + p], perm(col) = (col&3)*256 + (col>>2).
// ---------------------------------------------------------------------------
__global__ __launch_bounds__(256) void wih_pack_kernel(const float* __restrict__ WihF,
                                                       const float* __restrict__ WihB,
                                                       uint* __restrict__ w16F,
                                                       uint* __restrict__ w16B) {
    int id = blockIdx.x * 256 + threadIdx.x;   // 0..262143
    const float* W = WihF; uint* dst = w16F;
    if (id >= 131072) { id -= 131072; W = WihB; dst = w16B; }
    int col = id >> 7;
    int p = id & 127;
    int perm = ((col & 3) << 8) + (col >> 2);
    const float* row = W + ((size_t)perm << 8);
    dst[(col << 7) + p] = packh2(row[2 * p], row[2 * p + 1]);
}

// ---------------------------------------------------------------------------
// gemm_gx: fp16-pair dot2 GEMM. gx_il[row][col] = emb[row].Wih[perm(col)] +
// bias[perm(col)]. 64x64 tile, 32 k per iter, 4x4/thread. Skips masked tiles.
// grid = (512, 16)
// ---------------------------------------------------------------------------
__global__ __launch_bounds__(256) void gemm_gx_kernel(const int* __restrict__ widx,
                                                      const int* __restrict__ lens,
                                                      const float* __restrict__ wvec,
                                                      const uint* __restrict__ wih16,
                                                      const float* __restrict__ bias,
                                                      _Float16* __restrict__ gx) {
    int row0 = blockIdx.x * 64;
    int b = row0 >> 9;
    int t0 = row0 & 511;
    if (t0 >= lens[b]) return;
    int n0 = blockIdx.y * 64;

    __shared__ __align__(16) uint As[16][68];
    __shared__ __align__(16) uint Bs[16][68];
    __shared__ int aoff[64];

    int tid = threadIdx.x;
    if (tid < 64) aoff[tid] = widx[row0 + tid] << 8;
    __syncthreads();

    float acc[4][4] = {};
    int tn = tid & 15, tm = tid >> 4;

    for (int k0p = 0; k0p < 128; k0p += 16) {
#pragma unroll
        for (int p = 0; p < 4; ++p) {
            int lin = p * 256 + tid;
            int kp = lin & 15, m = lin >> 4;
            const float2 av = *reinterpret_cast<const float2*>(
                &wvec[aoff[m] + ((k0p + kp) << 1)]);
            As[kp][m] = packh2(av.x, av.y);
            Bs[kp][m] = wih16[((n0 + m) << 7) + k0p + kp];
        }
        __syncthreads();
#pragma unroll
        for (int kp = 0; kp < 16; ++kp) {
            uint4 a4 = *reinterpret_cast<const uint4*>(&As[kp][tm * 4]);
            uint4 b4 = *reinterpret_cast<const uint4*>(&Bs[kp][tn * 4]);
            uint am[4] = {a4.x, a4.y, a4.z, a4.w};
            uint bn[4] = {b4.x, b4.y, b4.z, b4.w};
#pragma unroll
            for (int i = 0; i < 4; ++i)
#pragma unroll
                for (int j = 0; j < 4; ++j) acc[i][j] = dot2f(am[i], bn[j], acc[i][j]);
        }
        __syncthreads();
    }

#pragma unroll
    for (int i = 0; i < 4; ++i) {
        int row = row0 + tm * 4 + i;
        ushort u[4];
#pragma unroll
        for (int j = 0; j < 4; ++j) {
            int col = n0 + tn * 4 + j;
            int perm = ((col & 3) << 8) + (col >> 2);
            u[j] = __builtin_bit_cast(ushort, (_Float16)(acc[i][j] + bias[perm]));
        }
        uint2 st;
        st.x = (uint)u[0] | ((uint)u[1] << 16);
        st.y = (uint)u[2] | ((uint)u[3] << 16);
        *reinterpret_cast<uint2*>(&gx[row * 1024 + n0 + tn * 4]) = st;
    }
}

// ---------------------------------------------------------------------------
// lstm_kernel: one block per (b, dir); 512 threads. Thread 2j+s owns gate
// rows {2s, 2s+1} of hidden j. W_hh fp16 resident: 96 k-pairs/gate as 192
// NAMED SCALAR uints in plain VGPRs + 32 k-pairs in LDS (128 KB).
// __launch_bounds__(512, 2): min-2-waves/EU is the ONLY occupancy hint the
// backend honors (round-2 evidence: two-arg form gave VGPR 212; round-3
// bare attribute gave 116). Budget 256 >= need ~222 -> full W residence.
// h broadcast via v_readlane; gate halves via __shfl_xor; feats store after
// the barrier (drains a full step later).
// ---------------------------------------------------------------------------
__global__ __launch_bounds__(512, 2)
void lstm_kernel(const _Float16* __restrict__ gx0,
                 const _Float16* __restrict__ gx1,
                 const uint* __restrict__ wreg0,
                 const uint* __restrict__ wreg1,
                 const uint* __restrict__ wlds0,
                 const uint* __restrict__ wlds1,
                 const int* __restrict__ lens,
                 float* __restrict__ feats) {
    int dir = blockIdx.x & 1;
    int b = blockIdx.x >> 1;
    const uint* gxu = reinterpret_cast<const uint*>(dir ? gx1 : gx0) + ((size_t)(b << 9) << 9);
    const uint* wreg = dir ? wreg1 : wreg0;
    const uint* wlds = dir ? wlds1 : wlds0;
    int len = lens[b];
    int tid = threadIdx.x;
    int lane = tid & 63;
    int sg = tid & 1;

    __shared__ __align__(16) uint lw[WLDS_UINTS];    // 128 KB LDS W chunk
    __shared__ __align__(16) uint hpair[2][128];     // fp16-pair h, dbuf

    for (int i = tid; i < WLDS_UINTS; i += 512) lw[i] = wlds[i];

    R96(WDECL)            // uint wA0..wA95, wB0..wB95 — named scalars
    R96(WLOAD)
    __syncthreads();

    float c = 0.0f;
    uint r0 = 0, r1 = 0;
    int pp = 0;

    int t0i = dir ? (len - 1) : 0;
    uint g = gxu[(t0i << 9) + tid];

    for (int tp = 0; tp < len; ++tp) {
        int t = dir ? (len - 1 - tp) : tp;
        int tnn = dir ? (len - 2 - tp) : (tp + 1);
        tnn = tnn < 0 ? 0 : (tnn >= len ? len - 1 : tnn);
        uint gnext = gxu[(tnn << 9) + tid];

        half2_t gv = __builtin_bit_cast(half2_t, g);
        float aA = (float)gv.x;
        float aB = (float)gv.y;

        R96(WSTEP)        // k-pairs 0..95: W in VGPRs, h via readlane
        R16(LSTEP)        // k-pairs 96..127: W in LDS

        // s=0: pA=sigm(i), pB=sigm(f) ; s=1: pA=tanh(g), pB=sigm(o)
        float y = sg ? aA + aA : aA;
        float sgm = __fdividef(1.0f, 1.0f + __expf(-y));
        float pA = sg ? sgm + sgm - 1.0f : sgm;
        float pB = sigm(aB);

        float oA = __shfl_xor(pA, 1);
        float oB = __shfl_xor(pB, 1);
        float si = sg ? oA : pA;
        float sf = sg ? oB : pB;
        float tg = sg ? pA : oA;
        float so = sg ? pB : oB;

        c = sf * c + si * tg;
        float h = so * tanh_fast(c);

        if (!sg) {
            reinterpret_cast<ushort*>(hpair[pp])[tid >> 1] =
                __builtin_bit_cast(ushort, (_Float16)h);
        }
        __syncthreads();
        // global store after the barrier: drains at the NEXT barrier
        if (!sg) {
            feats[(size_t)(((b << 9) + t)) * 512 + (dir << 8) + (tid >> 1)] = h;
        }
        r0 = hpair[pp][lane];
        r1 = hpair[pp][64 + lane];
        pp ^= 1;
        g = gnext;
    }
}

// ---------------------------------------------------------------------------
// emis_kernel: emissions[b,t,k] = feats[b,t,:] . W_out[k,:] + b_out[k]
// ---------------------------------------------------------------------------
__global__ __launch_bounds__(64) void emis_kernel(const float* __restrict__ feats,
                                                  const float* __restrict__ Wout,
                                                  const float* __restrict__ bout,
                                                  const int* __restrict__ lens,
                                                  float* __restrict__ emis) {
    int r = blockIdx.x;
    int b = r >> 9, t = r & 511;
    if (t >= lens[b]) return;
    int lane = threadIdx.x;
    const float* fr = feats + (size_t)r * 512;
    float f[8];
#pragma unroll
    for (int i = 0; i < 8; ++i) f[i] = fr[i * 64 + lane];
#pragma unroll
    for (int k = 0; k < 9; ++k) {
        float p = 0.0f;
#pragma unroll
        for (int i = 0; i < 8; ++i) p = fmaf(f[i], Wout[k * 512 + i * 64 + lane], p);
#pragma unroll
        for (int off = 32; off; off >>= 1) p += __shfl_down(p, off);
        if (lane == 0) emis[r * 9 + k] = p + bout[k];
    }
}

// ---------------------------------------------------------------------------
// crf_kernel: alpha recursion + viterbi + backtrace + numerator + loss.
// ---------------------------------------------------------------------------
__global__ __launch_bounds__(64) void crf_kernel(const float* __restrict__ emis,
                                                 const int* __restrict__ lens,
                                                 const int* __restrict__ labels,
                                                 const float* __restrict__ start_trans,
                                                 const float* __restrict__ end_trans,
                                                 const float* __restrict__ trans,
                                                 float* __restrict__ out) {
    int b = blockIdx.x;
    int len = lens[b];
    int lane = threadIdx.x;
    __shared__ float alpha[9], vit[9];
    __shared__ unsigned char hist[512 * 9];
    const float* eb = emis + b * 512 * 9;
    const int* lb = labels + b * 512;

    float tr[9];
    if (lane < 9) {
#pragma unroll
        for (int i = 0; i < 9; ++i) tr[i] = trans[i * 9 + lane];
        float s0 = start_trans[lane] + eb[lane];
        alpha[lane] = s0;
        vit[lane] = s0;
    }
    __syncthreads();

    for (int t = 1; t < len; ++t) {
        float na = 0.0f, nv = 0.0f;
        if (lane < 9) {
            float e = eb[t * 9 + lane];
            float a[9];
#pragma unroll
            for (int i = 0; i < 9; ++i) a[i] = alpha[i] + tr[i];
            float m = a[0];
#pragma unroll
            for (int i = 1; i < 9; ++i) m = fmaxf(m, a[i]);
            float s = 0.0f;
#pragma unroll
            for (int i = 0; i < 9; ++i) s += __expf(a[i] - m);
            na = m + __logf(s) + e;
            float bv = vit[0] + tr[0];
            int bi = 0;
#pragma unroll
            for (int i = 1; i < 9; ++i) {
                float x = vit[i] + tr[i];
                if (x > bv) { bv = x; bi = i; }
            }
            nv = bv + e;
            hist[t * 9 + lane] = (unsigned char)bi;
        }
        __syncthreads();
        if (lane < 9) { alpha[lane] = na; vit[lane] = nv; }
        __syncthreads();
    }

    float part = 0.0f;
    for (int t = 1 + lane; t < len; t += 64) {
        int yp = lb[t - 1], y = lb[t];
        part += trans[yp * 9 + y] + eb[t * 9 + y];
    }
#pragma unroll
    for (int off = 32; off; off >>= 1) part += __shfl_down(part, off);

    if (lane == 0) {
        int y0 = lb[0];
        float num = start_trans[y0] + eb[y0] + part + end_trans[lb[len - 1]];
        float m = alpha[0] + end_trans[0];
        for (int j = 1; j < 9; ++j) m = fmaxf(m, alpha[j] + end_trans[j]);
        float s = 0.0f;
        for (int j = 0; j < 9; ++j) s += __expf(alpha[j] + end_trans[j] - m);
        float denom = m + __logf(s);
        atomicAdd(out, (denom - num) * (1.0f / 64.0f));

        float bm = vit[0] + end_trans[0];
        int cur = 0;
        for (int j = 1; j < 9; ++j) {
            float x = vit[j] + end_trans[j];
            if (x > bm) { bm = x; cur = j; }
        }
        float* preds = out + 1 + b * 512;
        preds[len - 1] = (float)cur;
        for (int t = len - 1; t >= 1; --t) {
            cur = hist[t * 9 + cur];
            preds[t - 1] = (float)cur;
        }
    }
}

// ---------------------------------------------------------------------------
extern "C" void kernel_launch(void* const* d_in, const int* in_sizes, int n_in,
                              void* d_out, int out_size, void* d_ws, size_t ws_size,
                              hipStream_t stream) {
    const int* widx = (const int*)d_in[0];
    const int* lens = (const int*)d_in[1];
    const int* labels = (const int*)d_in[2];
    const float* wvec = (const float*)d_in[3];
    const float* WihF = (const float*)d_in[4];
    const float* WhhF = (const float*)d_in[5];
    const float* bF = (const float*)d_in[6];
    const float* WihB = (const float*)d_in[7];
    const float* WhhB = (const float*)d_in[8];
    const float* bB = (const float*)d_in[9];
    const float* Wout = (const float*)d_in[10];
    const float* bout = (const float*)d_in[11];
    const float* start_trans = (const float*)d_in[12];
    const float* end_trans = (const float*)d_in[13];
    const float* trans9 = (const float*)d_in[14];
    float* out = (float*)d_out;
    char* ws = (char*)d_ws;

    // workspace layout (bytes)
    _Float16* gxF = (_Float16*)(ws);                        // 67,108,864
    _Float16* gxB = (_Float16*)(ws + 67108864);             // 67,108,864
    uint* wregF   = (uint*)(ws + 134217728);                // 393,216
    uint* wregB   = (uint*)(ws + 134610944);                // 393,216
    uint* wldsF   = (uint*)(ws + 135004160);                // 131,072
    uint* wldsB   = (uint*)(ws + 135135232);                // 131,072
    // wih16F/B live only before lstm; emis written after lstm -> safe alias
    uint* wih16F  = (uint*)(ws + 135266304);                // 524,288
    uint* wih16B  = (uint*)(ws + 135790592);                // 524,288
    float* emis   = (float*)(ws + 135266304);               // 1,179,648 (alias)
    (void)in_sizes; (void)n_in; (void)out_size; (void)ws_size;

    float* feats = out + 1 + 32768;   // feats output region (B,T,512) fp32

    zero_kernel<<<65665, 256, 0, stream>>>(out, lens);
    pack_kernel<<<1024, 256, 0, stream>>>(WhhF, WhhB, wregF, wregB, wldsF, wldsB);
    wih_pack_kernel<<<1024, 256, 0, stream>>>(WihF, WihB, wih16F, wih16B);

    dim3 ggrid(512, 16);
    gemm_gx_kernel<<<ggrid, 256, 0, stream>>>(widx, lens, wvec, wih16F, bF, gxF);
    gemm_gx_kernel<<<ggrid, 256, 0, stream>>>(widx, lens, wvec, wih16B, bB, gxB);

    lstm_kernel<<<128, 512, 0, stream>>>(gxF, gxB, wregF, wregB, wldsF, wldsB, lens, feats);

    emis_kernel<<<32768, 64, 0, stream>>>(feats, Wout, bout, lens, emis);
    crf_kernel<<<64, 64, 0, stream>>>(emis, lens, labels, start_trans, end_trans, trans9, out);
}

// Round 5
// 1639.922 us; speedup vs baseline: 1.3005x; 1.0155x over previous
//
#include <hip/hip_runtime.h>
#include <hip/hip_bf16.h>
#include <math.h>

#ifndef __has_builtin
#define __has_builtin(x) 0
#endif

typedef unsigned int uint;
typedef unsigned short ushort;
typedef _Float16 half2_t __attribute__((ext_vector_type(2)));

// Problem constants: B=64, T=512, V=30000, E=256, H=256, K=9. 4H = 1024.
//
// ALLOCATOR MODEL (rounds 0-4, final): the backend budgets VGPRs for
// 2 workgroups/CU, LDS-blind, and IGNORES every occupancy hint:
//   512-thr -> cap 128 (observed 116, rounds 0/3/4 — launch_bounds(512,2)
//   and amdgpu_waves_per_eu both no-ops); 256-thr -> cap 256 (observed 212,
//   round 2). asm-AGPRs count against the same budget (round 1: spilled).
// Full W residence needs 222 regs @512thr / 424 @256thr -> IMPOSSIBLE.
//
// THIS ROUND: design FOR cap-128. Three-tier W partition per (b,dir) block:
//   - REG    34 k-pairs (m  0..33): 68 named-scalar uints (+~30 working +
//            <=32 transient landing = ~128).
//   - LDS    38 k-pairs (m 34..71): 152 KB, ds_read_b128.
//   - STREAM 56 k-pairs (m 72..127): per step, 28 coalesced uint4 loads from
//            L2 (wstr is 224 KB/dir, L2-resident), software-pipelined in 7
//            batches of 4 with one compute phase between issue and consume.
// This replaces the allocator's serial scratch-spill reloads (the ~3200
// stall cyc/step) with prefetchable, coalesced L2 reads.
#define WREG_UINTS (34 * 2 * 512)          // 34816
#define WLDS_U4    (19 * 512)              // 9728 uint4 = 155648 B
#define WSTR_U4    (28 * 512)              // 14336 uint4 = 229376 B

__device__ __forceinline__ float sigm(float x) {
    return __fdividef(1.0f, 1.0f + __expf(-x));
}
__device__ __forceinline__ float tanh_fast(float x) {
    float sg = __fdividef(1.0f, 1.0f + __expf(-2.0f * x));
    return sg + sg - 1.0f;
}
__device__ __forceinline__ float dot2f(uint w, uint h, float acc) {
#if __has_builtin(__builtin_amdgcn_fdot2)
    return __builtin_amdgcn_fdot2(__builtin_bit_cast(half2_t, w),
                                  __builtin_bit_cast(half2_t, h), acc, false);
#else
    half2_t a = __builtin_bit_cast(half2_t, w);
    half2_t b = __builtin_bit_cast(half2_t, h);
    return acc + (float)a.x * (float)b.x + (float)a.y * (float)b.y;
#endif
}
__device__ __forceinline__ uint packh2(float a, float b) {
    ushort u0 = __builtin_bit_cast(ushort, (_Float16)a);
    ushort u1 = __builtin_bit_cast(ushort, (_Float16)b);
    return (uint)u0 | ((uint)u1 << 16);
}

// ---- preprocessor repetition ------------------------------------------------
#define R34(X) \
  X(0) X(1) X(2) X(3) X(4) X(5) X(6) X(7) \
  X(8) X(9) X(10) X(11) X(12) X(13) X(14) X(15) \
  X(16) X(17) X(18) X(19) X(20) X(21) X(22) X(23) \
  X(24) X(25) X(26) X(27) X(28) X(29) X(30) X(31) \
  X(32) X(33)

// h pairs: r0 = pair(lane), r1 = pair(64+lane). Pair coverage:
//   REG    m 0..33  -> r0 lanes 0..33
//   LDS    p 34..71 -> r0 lanes 34..63 (p<64), r1 lanes 0..7 (p>=64)
//   STREAM p 72..127-> r1 lanes 8..63
#define WDECL(m) uint wA##m, wB##m;
#define WLOAD(m) wA##m = wreg[(2 * (m)) * 512 + tid]; \
                 wB##m = wreg[(2 * (m) + 1) * 512 + tid];
#define WSTEP(m) { \
    uint hp = (uint)__builtin_amdgcn_readlane((int)r0, (m)); \
    aA = dot2f(wA##m, hp, aA); \
    aB = dot2f(wB##m, hp, aB); }
// LSTEP(i): pairs 34+2i, 35+2i (both on same side of the 64 boundary since
// 34+2i is even; i<=14 -> r0, i>=15 -> r1).
#define LSTEP(i) { \
    uint4 w4 = lw4[(i) * 512 + tid]; \
    uint hp0 = (uint)__builtin_amdgcn_readlane( \
        (int)((34 + 2 * (i)) < 64 ? r0 : r1), (34 + 2 * (i)) & 63); \
    uint hp1 = (uint)__builtin_amdgcn_readlane( \
        (int)((35 + 2 * (i)) < 64 ? r0 : r1), (35 + 2 * (i)) & 63); \
    aA = dot2f(w4.x, hp0, aA); \
    aB = dot2f(w4.y, hp0, aB); \
    aA = dot2f(w4.z, hp1, aA); \
    aB = dot2f(w4.w, hp1, aB); }
// Stream: batch of 4 uint4 issued one compute-phase before consumption.
#define SISSUE(a, b, c, d, k0) { \
    a = wstr4[((k0) + 0) * 512 + tid]; \
    b = wstr4[((k0) + 1) * 512 + tid]; \
    c = wstr4[((k0) + 2) * 512 + tid]; \
    d = wstr4[((k0) + 3) * 512 + tid]; }
// SPAIR(u,k): pairs 72+2k, 73+2k -> r1 lanes 8+2k, 9+2k.
#define SPAIR(u, k) { \
    uint hp0 = (uint)__builtin_amdgcn_readlane((int)r1, 8 + 2 * (k)); \
    uint hp1 = (uint)__builtin_amdgcn_readlane((int)r1, 9 + 2 * (k)); \
    aA = dot2f(u.x, hp0, aA); \
    aB = dot2f(u.y, hp0, aB); \
    aA = dot2f(u.z, hp1, aA); \
    aB = dot2f(u.w, hp1, aB); }
#define SCONS(a, b, c, d, k0) \
    SPAIR(a, (k0) + 0) SPAIR(b, (k0) + 1) SPAIR(c, (k0) + 2) SPAIR(d, (k0) + 3)

// ---------------------------------------------------------------------------
// zero_kernel: zero loss, preds, and feats rows with t >= len (masked region).
// ---------------------------------------------------------------------------
__global__ __launch_bounds__(256) void zero_kernel(float* __restrict__ out,
                                                   const int* __restrict__ lens) {
    int bid = blockIdx.x;
    if (bid < 65536) {
        int g = bid * 256 + threadIdx.x;
        int row = g >> 9;
        int t = row & 511;
        int b = row >> 9;
        if (t >= lens[b]) out[32769 + g] = 0.0f;
    } else if (bid < 65536 + 128) {
        int p = (bid - 65536) * 256 + threadIdx.x;
        out[1 + p] = 0.0f;
    } else if (threadIdx.x == 0) {
        out[0] = 0.0f;
    }
}

// ---------------------------------------------------------------------------
// pack_kernel: W_hh (4H,H) fp32 -> fp16 k-pair-packed, three destinations.
// Flat uint id per dir: m = id>>10 (k-pair), r = id&1023, x = r>>9 (gate
// half), tl = r&511 (thread). Thread tl=2j+s owns gates q=2s+x of hidden j.
//   m<34        -> wreg[(2m+x)*512 + tl]
//   34<=m<72    -> mL=m-34: wlds[( (mL>>1)*512 + tl )*4 + ((mL&1)*2+x)]
//   m>=72       -> mS=m-72: wstr[( (mS>>1)*512 + tl )*4 + ((mS&1)*2+x)]
// Per-direction ids: 131072. grid = 1024 x 256 covers 2 dirs.
// ---------------------------------------------------------------------------
__global__ __launch_bounds__(256) void pack_kernel(const float* __restrict__ WF,
                                                   const float* __restrict__ WB,
                                                   uint* __restrict__ wregF,
                                                   uint* __restrict__ wregB,
                                                   uint* __restrict__ wldsF,
                                                   uint* __restrict__ wldsB,
                                                   uint* __restrict__ wstrF,
                                                   uint* __restrict__ wstrB) {
    int id = blockIdx.x * 256 + threadIdx.x;   // 0..262143
    const float* W = WF; uint* wr = wregF; uint* wl = wldsF; uint* wsp = wstrF;
    if (id >= 131072) { id -= 131072; W = WB; wr = wregB; wl = wldsB; wsp = wstrB; }
    int m = id >> 10;
    int r = id & 1023;
    int x = r >> 9;
    int tl = r & 511;
    int j = tl >> 1, s = tl & 1;
    int q = (s << 1) + x;
    const float* row = W + ((size_t)((q << 8) + j) << 8);
    uint pk = packh2(row[2 * m], row[2 * m + 1]);
    if (m < 34) {
        wr[((m << 1) + x) * 512 + tl] = pk;
    } else if (m < 72) {
        int mL = m - 34;
        wl[(((mL >> 1) << 9) + tl) * 4 + ((mL & 1) << 1) + x] = pk;
    } else {
        int mS = m - 72;
        wsp[(((mS >> 1) << 9) + tl) * 4 + ((mS & 1) << 1) + x] = pk;
    }
}

// ---------------------------------------------------------------------------
// wih_pack_kernel: Wih fp32 -> fp16 k-pair packed, indexed by interleaved
// output column: wih16[col*128 + p], perm(col) = (col&3)*256 + (col>>2).
// ---------------------------------------------------------------------------
__global__ __launch_bounds__(256) void wih_pack_kernel(const float* __restrict__ WihF,
                                                       const float* __restrict__ WihB,
                                                       uint* __restrict__ w16F,
                                                       uint* __restrict__ w16B) {
    int id = blockIdx.x * 256 + threadIdx.x;   // 0..262143
    const float* W = WihF; uint* dst = w16F;
    if (id >= 131072) { id -= 131072; W = WihB; dst = w16B; }
    int col = id >> 7;
    int p = id & 127;
    int perm = ((col & 3) << 8) + (col >> 2);
    const float* row = W + ((size_t)perm << 8);
    dst[(col << 7) + p] = packh2(row[2 * p], row[2 * p + 1]);
}

// ---------------------------------------------------------------------------
// gemm_gx: fp16-pair dot2 GEMM. gx_il[row][col] = emb[row].Wih[perm(col)] +
// bias[perm(col)]. 64x64 tile, 32 k per iter, 4x4/thread. Skips masked tiles.
// grid = (512, 16)
// ---------------------------------------------------------------------------
__global__ __launch_bounds__(256) void gemm_gx_kernel(const int* __restrict__ widx,
                                                      const int* __restrict__ lens,
                                                      const float* __restrict__ wvec,
                                                      const uint* __restrict__ wih16,
                                                      const float* __restrict__ bias,
                                                      _Float16* __restrict__ gx) {
    int row0 = blockIdx.x * 64;
    int b = row0 >> 9;
    int t0 = row0 & 511;
    if (t0 >= lens[b]) return;
    int n0 = blockIdx.y * 64;

    __shared__ __align__(16) uint As[16][68];
    __shared__ __align__(16) uint Bs[16][68];
    __shared__ int aoff[64];

    int tid = threadIdx.x;
    if (tid < 64) aoff[tid] = widx[row0 + tid] << 8;
    __syncthreads();

    float acc[4][4] = {};
    int tn = tid & 15, tm = tid >> 4;

    for (int k0p = 0; k0p < 128; k0p += 16) {
#pragma unroll
        for (int p = 0; p < 4; ++p) {
            int lin = p * 256 + tid;
            int kp = lin & 15, m = lin >> 4;
            const float2 av = *reinterpret_cast<const float2*>(
                &wvec[aoff[m] + ((k0p + kp) << 1)]);
            As[kp][m] = packh2(av.x, av.y);
            Bs[kp][m] = wih16[((n0 + m) << 7) + k0p + kp];
        }
        __syncthreads();
#pragma unroll
        for (int kp = 0; kp < 16; ++kp) {
            uint4 a4 = *reinterpret_cast<const uint4*>(&As[kp][tm * 4]);
            uint4 b4 = *reinterpret_cast<const uint4*>(&Bs[kp][tn * 4]);
            uint am[4] = {a4.x, a4.y, a4.z, a4.w};
            uint bn[4] = {b4.x, b4.y, b4.z, b4.w};
#pragma unroll
            for (int i = 0; i < 4; ++i)
#pragma unroll
                for (int j = 0; j < 4; ++j) acc[i][j] = dot2f(am[i], bn[j], acc[i][j]);
        }
        __syncthreads();
    }

#pragma unroll
    for (int i = 0; i < 4; ++i) {
        int row = row0 + tm * 4 + i;
        ushort u[4];
#pragma unroll
        for (int j = 0; j < 4; ++j) {
            int col = n0 + tn * 4 + j;
            int perm = ((col & 3) << 8) + (col >> 2);
            u[j] = __builtin_bit_cast(ushort, (_Float16)(acc[i][j] + bias[perm]));
        }
        uint2 st;
        st.x = (uint)u[0] | ((uint)u[1] << 16);
        st.y = (uint)u[2] | ((uint)u[3] << 16);
        *reinterpret_cast<uint2*>(&gx[row * 1024 + n0 + tn * 4]) = st;
    }
}

// ---------------------------------------------------------------------------
// lstm_kernel: one block per (b, dir); 512 threads. Thread 2j+s owns gate
// rows {2s, 2s+1} of hidden j. W_hh fp16 in three tiers (see header):
// 34 pairs named scalars, 38 pairs LDS, 56 pairs streamed per step from L2
// in 7 batches of 4 coalesced uint4 loads, double-buffered landing regs,
// issue one compute-phase ahead of consumption (latency ~= phase length).
// h broadcast via v_readlane; gate halves via __shfl_xor; feats store after
// the barrier (drains a full step later).
// ---------------------------------------------------------------------------
__global__ __launch_bounds__(512)
void lstm_kernel(const _Float16* __restrict__ gx0,
                 const _Float16* __restrict__ gx1,
                 const uint* __restrict__ wreg0,
                 const uint* __restrict__ wreg1,
                 const uint* __restrict__ wlds0,
                 const uint* __restrict__ wlds1,
                 const uint* __restrict__ wstr0,
                 const uint* __restrict__ wstr1,
                 const int* __restrict__ lens,
                 float* __restrict__ feats) {
    int dir = blockIdx.x & 1;
    int b = blockIdx.x >> 1;
    const uint* gxu = reinterpret_cast<const uint*>(dir ? gx1 : gx0) + ((size_t)(b << 9) << 9);
    const uint* wreg = dir ? wreg1 : wreg0;
    const uint4* wlds4 = reinterpret_cast<const uint4*>(dir ? wlds1 : wlds0);
    const uint4* wstr4 = reinterpret_cast<const uint4*>(dir ? wstr1 : wstr0);
    int len = lens[b];
    int tid = threadIdx.x;
    int lane = tid & 63;
    int sg = tid & 1;

    __shared__ __align__(16) uint4 lw4[WLDS_U4];     // 152 KB LDS W chunk
    __shared__ __align__(16) uint hpair[2][128];     // fp16-pair h, dbuf

    for (int i = tid; i < WLDS_U4; i += 512) lw4[i] = wlds4[i];

    R34(WDECL)            // uint wA0..wA33, wB0..wB33 — named scalars
    R34(WLOAD)
    __syncthreads();

    float c = 0.0f;
    uint r0 = 0, r1 = 0;
    int pp = 0;

    int t0i = dir ? (len - 1) : 0;
    uint g = gxu[(t0i << 9) + tid];

    for (int tp = 0; tp < len; ++tp) {
        int t = dir ? (len - 1 - tp) : tp;
        int tnn = dir ? (len - 2 - tp) : (tp + 1);
        tnn = tnn < 0 ? 0 : (tnn >= len ? len - 1 : tnn);
        uint gnext = gxu[(tnn << 9) + tid];

        half2_t gv = __builtin_bit_cast(half2_t, g);
        float aA = (float)gv.x;
        float aB = (float)gv.y;

        uint4 sA0, sA1, sA2, sA3;      // landing buffer A
        uint4 sB0, sB1, sB2, sB3;      // landing buffer B

        SISSUE(sA0, sA1, sA2, sA3, 0)
        WSTEP(0)  WSTEP(1)  WSTEP(2)  WSTEP(3)  WSTEP(4)  WSTEP(5)
        WSTEP(6)  WSTEP(7)  WSTEP(8)  WSTEP(9)  WSTEP(10) WSTEP(11)
        WSTEP(12) WSTEP(13) WSTEP(14) WSTEP(15) WSTEP(16)
        SISSUE(sB0, sB1, sB2, sB3, 4)
        SCONS(sA0, sA1, sA2, sA3, 0)
        WSTEP(17) WSTEP(18) WSTEP(19) WSTEP(20) WSTEP(21) WSTEP(22)
        WSTEP(23) WSTEP(24) WSTEP(25) WSTEP(26) WSTEP(27) WSTEP(28)
        WSTEP(29) WSTEP(30) WSTEP(31) WSTEP(32) WSTEP(33)
        SISSUE(sA0, sA1, sA2, sA3, 8)
        SCONS(sB0, sB1, sB2, sB3, 4)
        LSTEP(0) LSTEP(1) LSTEP(2) LSTEP(3) LSTEP(4) LSTEP(5) LSTEP(6)
        SISSUE(sB0, sB1, sB2, sB3, 12)
        SCONS(sA0, sA1, sA2, sA3, 8)
        LSTEP(7) LSTEP(8) LSTEP(9) LSTEP(10) LSTEP(11) LSTEP(12)
        SISSUE(sA0, sA1, sA2, sA3, 16)
        SCONS(sB0, sB1, sB2, sB3, 12)
        LSTEP(13) LSTEP(14) LSTEP(15) LSTEP(16) LSTEP(17) LSTEP(18)
        SISSUE(sB0, sB1, sB2, sB3, 20)
        SCONS(sA0, sA1, sA2, sA3, 16)
        SISSUE(sA0, sA1, sA2, sA3, 24)
        SCONS(sB0, sB1, sB2, sB3, 20)
        SCONS(sA0, sA1, sA2, sA3, 24)

        // s=0: pA=sigm(i), pB=sigm(f) ; s=1: pA=tanh(g), pB=sigm(o)
        float y = sg ? aA + aA : aA;
        float sgm = __fdividef(1.0f, 1.0f + __expf(-y));
        float pA = sg ? sgm + sgm - 1.0f : sgm;
        float pB = sigm(aB);

        float oA = __shfl_xor(pA, 1);
        float oB = __shfl_xor(pB, 1);
        float si = sg ? oA : pA;
        float sf = sg ? oB : pB;
        float tg = sg ? pA : oA;
        float so = sg ? pB : oB;

        c = sf * c + si * tg;
        float h = so * tanh_fast(c);

        if (!sg) {
            reinterpret_cast<ushort*>(hpair[pp])[tid >> 1] =
                __builtin_bit_cast(ushort, (_Float16)h);
        }
        __syncthreads();
        // global store after the barrier: drains at the NEXT barrier
        if (!sg) {
            feats[(size_t)(((b << 9) + t)) * 512 + (dir << 8) + (tid >> 1)] = h;
        }
        r0 = hpair[pp][lane];
        r1 = hpair[pp][64 + lane];
        pp ^= 1;
        g = gnext;
    }
}

// ---------------------------------------------------------------------------
// emis_kernel: emissions[b,t,k] = feats[b,t,:] . W_out[k,:] + b_out[k]
// ---------------------------------------------------------------------------
__global__ __launch_bounds__(64) void emis_kernel(const float* __restrict__ feats,
                                                  const float* __restrict__ Wout,
                                                  const float* __restrict__ bout,
                                                  const int* __restrict__ lens,
                                                  float* __restrict__ emis) {
    int r = blockIdx.x;
    int b = r >> 9, t = r & 511;
    if (t >= lens[b]) return;
    int lane = threadIdx.x;
    const float* fr = feats + (size_t)r * 512;
    float f[8];
#pragma unroll
    for (int i = 0; i < 8; ++i) f[i] = fr[i * 64 + lane];
#pragma unroll
    for (int k = 0; k < 9; ++k) {
        float p = 0.0f;
#pragma unroll
        for (int i = 0; i < 8; ++i) p = fmaf(f[i], Wout[k * 512 + i * 64 + lane], p);
#pragma unroll
        for (int off = 32; off; off >>= 1) p += __shfl_down(p, off);
        if (lane == 0) emis[r * 9 + k] = p + bout[k];
    }
}

// ---------------------------------------------------------------------------
// crf_kernel: alpha recursion + viterbi + backtrace + numerator + loss.
// ---------------------------------------------------------------------------
__global__ __launch_bounds__(64) void crf_kernel(const float* __restrict__ emis,
                                                 const int* __restrict__ lens,
                                                 const int* __restrict__ labels,
                                                 const float* __restrict__ start_trans,
                                                 const float* __restrict__ end_trans,
                                                 const float* __restrict__ trans,
                                                 float* __restrict__ out) {
    int b = blockIdx.x;
    int len = lens[b];
    int lane = threadIdx.x;
    __shared__ float alpha[9], vit[9];
    __shared__ unsigned char hist[512 * 9];
    const float* eb = emis + b * 512 * 9;
    const int* lb = labels + b * 512;

    float tr[9];
    if (lane < 9) {
#pragma unroll
        for (int i = 0; i < 9; ++i) tr[i] = trans[i * 9 + lane];
        float s0 = start_trans[lane] + eb[lane];
        alpha[lane] = s0;
        vit[lane] = s0;
    }
    __syncthreads();

    for (int t = 1; t < len; ++t) {
        float na = 0.0f, nv = 0.0f;
        if (lane < 9) {
            float e = eb[t * 9 + lane];
            float a[9];
#pragma unroll
            for (int i = 0; i < 9; ++i) a[i] = alpha[i] + tr[i];
            float m = a[0];
#pragma unroll
            for (int i = 1; i < 9; ++i) m = fmaxf(m, a[i]);
            float s = 0.0f;
#pragma unroll
            for (int i = 0; i < 9; ++i) s += __expf(a[i] - m);
            na = m + __logf(s) + e;
            float bv = vit[0] + tr[0];
            int bi = 0;
#pragma unroll
            for (int i = 1; i < 9; ++i) {
                float x = vit[i] + tr[i];
                if (x > bv) { bv = x; bi = i; }
            }
            nv = bv + e;
            hist[t * 9 + lane] = (unsigned char)bi;
        }
        __syncthreads();
        if (lane < 9) { alpha[lane] = na; vit[lane] = nv; }
        __syncthreads();
    }

    float part = 0.0f;
    for (int t = 1 + lane; t < len; t += 64) {
        int yp = lb[t - 1], y = lb[t];
        part += trans[yp * 9 + y] + eb[t * 9 + y];
    }
#pragma unroll
    for (int off = 32; off; off >>= 1) part += __shfl_down(part, off);

    if (lane == 0) {
        int y0 = lb[0];
        float num = start_trans[y0] + eb[y0] + part + end_trans[lb[len - 1]];
        float m = alpha[0] + end_trans[0];
        for (int j = 1; j < 9; ++j) m = fmaxf(m, alpha[j] + end_trans[j]);
        float s = 0.0f;
        for (int j = 0; j < 9; ++j) s += __expf(alpha[j] + end_trans[j] - m);
        float denom = m + __logf(s);
        atomicAdd(out, (denom - num) * (1.0f / 64.0f));

        float bm = vit[0] + end_trans[0];
        int cur = 0;
        for (int j = 1; j < 9; ++j) {
            float x = vit[j] + end_trans[j];
            if (x > bm) { bm = x; cur = j; }
        }
        float* preds = out + 1 + b * 512;
        preds[len - 1] = (float)cur;
        for (int t = len - 1; t >= 1; --t) {
            cur = hist[t * 9 + cur];
            preds[t - 1] = (float)cur;
        }
    }
}

// ---------------------------------------------------------------------------
extern "C" void kernel_launch(void* const* d_in, const int* in_sizes, int n_in,
                              void* d_out, int out_size, void* d_ws, size_t ws_size,
                              hipStream_t stream) {
    const int* widx = (const int*)d_in[0];
    const int* lens = (const int*)d_in[1];
    const int* labels = (const int*)d_in[2];
    const float* wvec = (const float*)d_in[3];
    const float* WihF = (const float*)d_in[4];
    const float* WhhF = (const float*)d_in[5];
    const float* bF = (const float*)d_in[6];
    const float* WihB = (const float*)d_in[7];
    const float* WhhB = (const float*)d_in[8];
    const float* bB = (const float*)d_in[9];
    const float* Wout = (const float*)d_in[10];
    const float* bout = (const float*)d_in[11];
    const float* start_trans = (const float*)d_in[12];
    const float* end_trans = (const float*)d_in[13];
    const float* trans9 = (const float*)d_in[14];
    float* out = (float*)d_out;
    char* ws = (char*)d_ws;

    // workspace layout (bytes)
    _Float16* gxF = (_Float16*)(ws);                        // 67,108,864
    _Float16* gxB = (_Float16*)(ws + 67108864);             // 67,108,864
    uint* wregF   = (uint*)(ws + 134217728);                // 139,264
    uint* wregB   = (uint*)(ws + 134356992);                // 139,264
    uint* wldsF   = (uint*)(ws + 134496256);                // 155,648
    uint* wldsB   = (uint*)(ws + 134651904);                // 155,648
    uint* wstrF   = (uint*)(ws + 134807552);                // 229,376
    uint* wstrB   = (uint*)(ws + 135036928);                // 229,376
    // wih16F/B live only before lstm; emis written after lstm -> safe alias
    uint* wih16F  = (uint*)(ws + 135266304);                // 524,288
    uint* wih16B  = (uint*)(ws + 135790592);                // 524,288
    float* emis   = (float*)(ws + 135266304);               // 1,179,648 (alias)
    (void)in_sizes; (void)n_in; (void)out_size; (void)ws_size;

    float* feats = out + 1 + 32768;   // feats output region (B,T,512) fp32

    zero_kernel<<<65665, 256, 0, stream>>>(out, lens);
    pack_kernel<<<1024, 256, 0, stream>>>(WhhF, WhhB, wregF, wregB, wldsF, wldsB,
                                          wstrF, wstrB);
    wih_pack_kernel<<<1024, 256, 0, stream>>>(WihF, WihB, wih16F, wih16B);

    dim3 ggrid(512, 16);
    gemm_gx_kernel<<<ggrid, 256, 0, stream>>>(widx, lens, wvec, wih16F, bF, gxF);
    gemm_gx_kernel<<<ggrid, 256, 0, stream>>>(widx, lens, wvec, wih16B, bB, gxB);

    lstm_kernel<<<128, 512, 0, stream>>>(gxF, gxB, wregF, wregB, wldsF, wldsB,
                                         wstrF, wstrB, lens, feats);

    emis_kernel<<<32768, 64, 0, stream>>>(feats, Wout, bout, lens, emis);
    crf_kernel<<<64, 64, 0, stream>>>(emis, lens, labels, start_trans, end_trans, trans9, out);
}

// Round 6
// 1621.410 us; speedup vs baseline: 1.3154x; 1.0114x over previous
//
#include <hip/hip_runtime.h>
#include <hip/hip_bf16.h>
#include <math.h>

#ifndef __has_builtin
#define __has_builtin(x) 0
#endif

typedef unsigned int uint;
typedef unsigned short ushort;
typedef _Float16 half2_t __attribute__((ext_vector_type(2)));

// Problem constants: B=64, T=512, V=30000, E=256, H=256, K=9. 4H = 1024.
//
// Round-5 pipe budget per block per step (measured 4683 cyc): VALU ~1900,
// LDS ~1830, L2-stream ~2040 — sum 5800, overlap only ~20%. This round:
// SAME three-tier idea, overlapped schedule:
//   REG    26 k-pairs (52 uints, named scalars)
//   LDS    38 k-pairs (19 uint4-groups, 152 KB), 2-deep d0/d1/d2 rotation
//   STREAM 64 k-pairs (32 uint4), 8 batches x 4, 2 landing sets, 1-phase
//          issue->consume distance; batches b0,b1 of step t+1 issued BEFORE
//          the barrier (stream addresses are t-invariant).
// Barrier = raw asm {s_waitcnt lgkmcnt(0); s_barrier}: __syncthreads'
// implicit vmcnt(0) would drain the cross-barrier prefetch; only LDS (hbuf
// ds_write) needs draining. feats store + stream loads fly across.
// h-pair lane map: REG m in r0 lanes 0..25, LDS pairs 26..63 in r0 lanes
// 26..63, STREAM pairs 64..127 in r1 lanes 0..63.
// VGPR ledger: 52 W + 32 landing + 12 lds-pipe + ~22 working ~= 118 <= 128
// (cap-128 is the allocator's fixed budget for 512-thr blocks, rounds 0-4).
#define WREG_UINTS (26 * 2 * 512)          // 26624
#define WLDS_U4    (19 * 512)              // 9728 uint4 = 155648 B
#define WSTR_U4    (32 * 512)              // 16384 uint4 = 262144 B

__device__ __forceinline__ float sigm(float x) {
    return __fdividef(1.0f, 1.0f + __expf(-x));
}
__device__ __forceinline__ float tanh_fast(float x) {
    float sg = __fdividef(1.0f, 1.0f + __expf(-2.0f * x));
    return sg + sg - 1.0f;
}
__device__ __forceinline__ float dot2f(uint w, uint h, float acc) {
#if __has_builtin(__builtin_amdgcn_fdot2)
    return __builtin_amdgcn_fdot2(__builtin_bit_cast(half2_t, w),
                                  __builtin_bit_cast(half2_t, h), acc, false);
#else
    half2_t a = __builtin_bit_cast(half2_t, w);
    half2_t b = __builtin_bit_cast(half2_t, h);
    return acc + (float)a.x * (float)b.x + (float)a.y * (float)b.y;
#endif
}
__device__ __forceinline__ uint packh2(float a, float b) {
    ushort u0 = __builtin_bit_cast(ushort, (_Float16)a);
    ushort u1 = __builtin_bit_cast(ushort, (_Float16)b);
    return (uint)u0 | ((uint)u1 << 16);
}

// ---- preprocessor repetition ------------------------------------------------
#define R26(X) \
  X(0) X(1) X(2) X(3) X(4) X(5) X(6) X(7) \
  X(8) X(9) X(10) X(11) X(12) X(13) X(14) X(15) \
  X(16) X(17) X(18) X(19) X(20) X(21) X(22) X(23) \
  X(24) X(25)

#define WDECL(m) uint wA##m, wB##m;
#define WLOAD(m) wA##m = wreg[(2 * (m)) * 512 + tid]; \
                 wB##m = wreg[(2 * (m) + 1) * 512 + tid];
#define WSTEP(m) { \
    uint hp = (uint)__builtin_amdgcn_readlane((int)r0, (m)); \
    aA = dot2f(wA##m, hp, aA); \
    aB = dot2f(wB##m, hp, aB); }

// LDS tier: group i (0..18) = pairs 26+2i, 27+2i (both r0 lanes).
#define LLOAD(dv, i) dv = lw4[(i) * 512 + tid];
#define LCONS(dv, i) { \
    uint hp0 = (uint)__builtin_amdgcn_readlane((int)r0, 26 + 2 * (i)); \
    uint hp1 = (uint)__builtin_amdgcn_readlane((int)r0, 27 + 2 * (i)); \
    aA = dot2f(dv.x, hp0, aA); \
    aB = dot2f(dv.y, hp0, aB); \
    aA = dot2f(dv.z, hp1, aA); \
    aB = dot2f(dv.w, hp1, aB); }

// Stream tier: uint4 group s (0..31) = pairs 64+2s, 65+2s (r1 lanes 2s, 2s+1)
#define SGRP(u, s) { \
    uint hp0 = (uint)__builtin_amdgcn_readlane((int)r1, 2 * (s)); \
    uint hp1 = (uint)__builtin_amdgcn_readlane((int)r1, 2 * (s) + 1); \
    aA = dot2f(u.x, hp0, aA); \
    aB = dot2f(u.y, hp0, aB); \
    aA = dot2f(u.z, hp1, aA); \
    aB = dot2f(u.w, hp1, aB); }
#define SISSUE(s0_, s1_, s2_, s3_, j) { \
    s0_ = wstr4[(4 * (j) + 0) * 512 + tid]; \
    s1_ = wstr4[(4 * (j) + 1) * 512 + tid]; \
    s2_ = wstr4[(4 * (j) + 2) * 512 + tid]; \
    s3_ = wstr4[(4 * (j) + 3) * 512 + tid]; }
#define SCONSB(s0_, s1_, s2_, s3_, j) \
    SGRP(s0_, 4 * (j) + 0) SGRP(s1_, 4 * (j) + 1) \
    SGRP(s2_, 4 * (j) + 2) SGRP(s3_, 4 * (j) + 3)

// ---------------------------------------------------------------------------
// zero_kernel: zero loss, preds, and feats rows with t >= len (masked region).
// ---------------------------------------------------------------------------
__global__ __launch_bounds__(256) void zero_kernel(float* __restrict__ out,
                                                   const int* __restrict__ lens) {
    int bid = blockIdx.x;
    if (bid < 65536) {
        int g = bid * 256 + threadIdx.x;
        int row = g >> 9;
        int t = row & 511;
        int b = row >> 9;
        if (t >= lens[b]) out[32769 + g] = 0.0f;
    } else if (bid < 65536 + 128) {
        int p = (bid - 65536) * 256 + threadIdx.x;
        out[1 + p] = 0.0f;
    } else if (threadIdx.x == 0) {
        out[0] = 0.0f;
    }
}

// ---------------------------------------------------------------------------
// pack_kernel: W_hh (4H,H) fp32 -> fp16 k-pair-packed, three destinations.
// Flat uint id per dir: m = id>>10 (k-pair 0..127), r = id&1023, x = r>>9
// (gate half), tl = r&511 (thread). Thread tl=2j+s owns gates q=2s+x of
// hidden j.
//   m<26        -> wreg[(2m+x)*512 + tl]
//   26<=m<64    -> mL=m-26: wlds[((mL>>1)*512 + tl)*4 + (mL&1)*2+x]
//   m>=64       -> mS=m-64: wstr[((mS>>1)*512 + tl)*4 + (mS&1)*2+x]
// grid = 1024 x 256 covers 2 dirs x 131072.
// ---------------------------------------------------------------------------
__global__ __launch_bounds__(256) void pack_kernel(const float* __restrict__ WF,
                                                   const float* __restrict__ WB,
                                                   uint* __restrict__ wregF,
                                                   uint* __restrict__ wregB,
                                                   uint* __restrict__ wldsF,
                                                   uint* __restrict__ wldsB,
                                                   uint* __restrict__ wstrF,
                                                   uint* __restrict__ wstrB) {
    int id = blockIdx.x * 256 + threadIdx.x;   // 0..262143
    const float* W = WF; uint* wr = wregF; uint* wl = wldsF; uint* wsp = wstrF;
    if (id >= 131072) { id -= 131072; W = WB; wr = wregB; wl = wldsB; wsp = wstrB; }
    int m = id >> 10;
    int r = id & 1023;
    int x = r >> 9;
    int tl = r & 511;
    int j = tl >> 1, s = tl & 1;
    int q = (s << 1) + x;
    const float* row = W + ((size_t)((q << 8) + j) << 8);
    uint pk = packh2(row[2 * m], row[2 * m + 1]);
    if (m < 26) {
        wr[((m << 1) + x) * 512 + tl] = pk;
    } else if (m < 64) {
        int mL = m - 26;
        wl[(((mL >> 1) << 9) + tl) * 4 + ((mL & 1) << 1) + x] = pk;
    } else {
        int mS = m - 64;
        wsp[(((mS >> 1) << 9) + tl) * 4 + ((mS & 1) << 1) + x] = pk;
    }
}

// ---------------------------------------------------------------------------
// wih_pack_kernel: Wih fp32 -> fp16 k-pair packed, indexed by interleaved
// output column: wih16[col*128 + p], perm(col) = (col&3)*256 + (col>>2).
// ---------------------------------------------------------------------------
__global__ __launch_bounds__(256) void wih_pack_kernel(const float* __restrict__ WihF,
                                                       const float* __restrict__ WihB,
                                                       uint* __restrict__ w16F,
                                                       uint* __restrict__ w16B) {
    int id = blockIdx.x * 256 + threadIdx.x;   // 0..262143
    const float* W = WihF; uint* dst = w16F;
    if (id >= 131072) { id -= 131072; W = WihB; dst = w16B; }
    int col = id >> 7;
    int p = id & 127;
    int perm = ((col & 3) << 8) + (col >> 2);
    const float* row = W + ((size_t)perm << 8);
    dst[(col << 7) + p] = packh2(row[2 * p], row[2 * p + 1]);
}

// ---------------------------------------------------------------------------
// gemm_gx: fp16-pair dot2 GEMM. gx_il[row][col] = emb[row].Wih[perm(col)] +
// bias[perm(col)]. 64x64 tile, 32 k per iter, 4x4/thread. Skips masked tiles.
// grid = (512, 16)
// ---------------------------------------------------------------------------
__global__ __launch_bounds__(256) void gemm_gx_kernel(const int* __restrict__ widx,
                                                      const int* __restrict__ lens,
                                                      const float* __restrict__ wvec,
                                                      const uint* __restrict__ wih16,
                                                      const float* __restrict__ bias,
                                                      _Float16* __restrict__ gx) {
    int row0 = blockIdx.x * 64;
    int b = row0 >> 9;
    int t0 = row0 & 511;
    if (t0 >= lens[b]) return;
    int n0 = blockIdx.y * 64;

    __shared__ __align__(16) uint As[16][68];
    __shared__ __align__(16) uint Bs[16][68];
    __shared__ int aoff[64];

    int tid = threadIdx.x;
    if (tid < 64) aoff[tid] = widx[row0 + tid] << 8;
    __syncthreads();

    float acc[4][4] = {};
    int tn = tid & 15, tm = tid >> 4;

    for (int k0p = 0; k0p < 128; k0p += 16) {
#pragma unroll
        for (int p = 0; p < 4; ++p) {
            int lin = p * 256 + tid;
            int kp = lin & 15, m = lin >> 4;
            const float2 av = *reinterpret_cast<const float2*>(
                &wvec[aoff[m] + ((k0p + kp) << 1)]);
            As[kp][m] = packh2(av.x, av.y);
            Bs[kp][m] = wih16[((n0 + m) << 7) + k0p + kp];
        }
        __syncthreads();
#pragma unroll
        for (int kp = 0; kp < 16; ++kp) {
            uint4 a4 = *reinterpret_cast<const uint4*>(&As[kp][tm * 4]);
            uint4 b4 = *reinterpret_cast<const uint4*>(&Bs[kp][tn * 4]);
            uint am[4] = {a4.x, a4.y, a4.z, a4.w};
            uint bn[4] = {b4.x, b4.y, b4.z, b4.w};
#pragma unroll
            for (int i = 0; i < 4; ++i)
#pragma unroll
                for (int j = 0; j < 4; ++j) acc[i][j] = dot2f(am[i], bn[j], acc[i][j]);
        }
        __syncthreads();
    }

#pragma unroll
    for (int i = 0; i < 4; ++i) {
        int row = row0 + tm * 4 + i;
        ushort u[4];
#pragma unroll
        for (int j = 0; j < 4; ++j) {
            int col = n0 + tn * 4 + j;
            int perm = ((col & 3) << 8) + (col >> 2);
            u[j] = __builtin_bit_cast(ushort, (_Float16)(acc[i][j] + bias[perm]));
        }
        uint2 st;
        st.x = (uint)u[0] | ((uint)u[1] << 16);
        st.y = (uint)u[2] | ((uint)u[3] << 16);
        *reinterpret_cast<uint2*>(&gx[row * 1024 + n0 + tn * 4]) = st;
    }
}

// ---------------------------------------------------------------------------
// lstm_kernel: one block per (b, dir); 512 threads. Thread 2j+s owns gate
// rows {2s, 2s+1} of hidden j. Three-tier W (26 reg / 38 LDS / 64 stream),
// fully software-pipelined; raw asm barrier keeps stream loads + feats
// store in flight across the step boundary.
// ---------------------------------------------------------------------------
__global__ __launch_bounds__(512)
void lstm_kernel(const _Float16* __restrict__ gx0,
                 const _Float16* __restrict__ gx1,
                 const uint* __restrict__ wreg0,
                 const uint* __restrict__ wreg1,
                 const uint* __restrict__ wlds0,
                 const uint* __restrict__ wlds1,
                 const uint* __restrict__ wstr0,
                 const uint* __restrict__ wstr1,
                 const int* __restrict__ lens,
                 float* __restrict__ feats) {
    int dir = blockIdx.x & 1;
    int b = blockIdx.x >> 1;
    const uint* gxu = reinterpret_cast<const uint*>(dir ? gx1 : gx0) + ((size_t)(b << 9) << 9);
    const uint* wreg = dir ? wreg1 : wreg0;
    const uint4* wlds4 = reinterpret_cast<const uint4*>(dir ? wlds1 : wlds0);
    const uint4* wstr4 = reinterpret_cast<const uint4*>(dir ? wstr1 : wstr0);
    int len = lens[b];
    int tid = threadIdx.x;
    int lane = tid & 63;
    int sg = tid & 1;

    __shared__ __align__(16) uint4 lw4[WLDS_U4];     // 152 KB LDS W chunk
    __shared__ __align__(16) uint hpair[2][128];     // fp16-pair h, dbuf

    for (int i = tid; i < WLDS_U4; i += 512) lw4[i] = wlds4[i];

    R26(WDECL)            // uint wA0..wA25, wB0..wB25 — named scalars
    R26(WLOAD)
    __syncthreads();

    float c = 0.0f;
    uint r0 = 0, r1 = 0;
    int pp = 0;

    int t0i = dir ? (len - 1) : 0;
    uint g = gxu[(t0i << 9) + tid];

    uint4 sA0, sA1, sA2, sA3;      // stream landing set A
    uint4 sB0, sB1, sB2, sB3;      // stream landing set B
    uint4 d0, d1, d2;              // LDS pipeline regs

    // prologue: batches b0, b1 in flight into the loop
    SISSUE(sA0, sA1, sA2, sA3, 0)
    SISSUE(sB0, sB1, sB2, sB3, 1)

    for (int tp = 0; tp < len; ++tp) {
        int t = dir ? (len - 1 - tp) : tp;
        int tnn = dir ? (len - 2 - tp) : (tp + 1);
        tnn = tnn < 0 ? 0 : (tnn >= len ? len - 1 : tnn);
        uint gnext = gxu[(tnn << 9) + tid];

        half2_t gv = __builtin_bit_cast(half2_t, g);
        float aA = (float)gv.x;
        float aB = (float)gv.y;

        LLOAD(d0, 0) LLOAD(d1, 1)
        WSTEP(0)  WSTEP(1)  WSTEP(2)  WSTEP(3)  WSTEP(4)  WSTEP(5)
        WSTEP(6)  WSTEP(7)  WSTEP(8)  WSTEP(9)  WSTEP(10) WSTEP(11)
        WSTEP(12)
        SCONSB(sA0, sA1, sA2, sA3, 0)       // b0 (in flight since prev step)
        SISSUE(sA0, sA1, sA2, sA3, 2)       // b2
        WSTEP(13) WSTEP(14) WSTEP(15) WSTEP(16) WSTEP(17) WSTEP(18)
        WSTEP(19) WSTEP(20) WSTEP(21) WSTEP(22) WSTEP(23) WSTEP(24)
        WSTEP(25)
        SCONSB(sB0, sB1, sB2, sB3, 1)       // b1
        SISSUE(sB0, sB1, sB2, sB3, 3)       // b3
        LLOAD(d2, 2)  LCONS(d0, 0)
        LLOAD(d0, 3)  LCONS(d1, 1)
        LLOAD(d1, 4)  LCONS(d2, 2)
        LLOAD(d2, 5)  LCONS(d0, 3)
        LLOAD(d0, 6)  LCONS(d1, 4)
        SCONSB(sA0, sA1, sA2, sA3, 2)       // b2
        SISSUE(sA0, sA1, sA2, sA3, 4)       // b4
        LLOAD(d1, 7)  LCONS(d2, 5)
        LLOAD(d2, 8)  LCONS(d0, 6)
        LLOAD(d0, 9)  LCONS(d1, 7)
        LLOAD(d1, 10) LCONS(d2, 8)
        LLOAD(d2, 11) LCONS(d0, 9)
        SCONSB(sB0, sB1, sB2, sB3, 3)       // b3
        SISSUE(sB0, sB1, sB2, sB3, 5)       // b5
        LLOAD(d0, 12) LCONS(d1, 10)
        LLOAD(d1, 13) LCONS(d2, 11)
        LLOAD(d2, 14) LCONS(d0, 12)
        LLOAD(d0, 15) LCONS(d1, 13)
        LLOAD(d1, 16) LCONS(d2, 14)
        SCONSB(sA0, sA1, sA2, sA3, 4)       // b4
        SISSUE(sA0, sA1, sA2, sA3, 6)       // b6
        LLOAD(d2, 17) LCONS(d0, 15)
        LLOAD(d0, 18) LCONS(d1, 16)
        LCONS(d2, 17) LCONS(d0, 18)
        SCONSB(sB0, sB1, sB2, sB3, 5)       // b5
        SISSUE(sB0, sB1, sB2, sB3, 7)       // b7
        SCONSB(sA0, sA1, sA2, sA3, 6)       // b6
        SCONSB(sB0, sB1, sB2, sB3, 7)       // b7

        // s=0: pA=sigm(i), pB=sigm(f) ; s=1: pA=tanh(g), pB=sigm(o)
        float y = sg ? aA + aA : aA;
        float sgm = __fdividef(1.0f, 1.0f + __expf(-y));
        float pA = sg ? sgm + sgm - 1.0f : sgm;
        float pB = sigm(aB);

        float oA = __shfl_xor(pA, 1);
        float oB = __shfl_xor(pB, 1);
        float si = sg ? oA : pA;
        float sf = sg ? oB : pB;
        float tg = sg ? pA : oA;
        float so = sg ? pB : oB;

        c = sf * c + si * tg;
        float h = so * tanh_fast(c);

        if (!sg) {
            reinterpret_cast<ushort*>(hpair[pp])[tid >> 1] =
                __builtin_bit_cast(ushort, (_Float16)h);
        }
        // prefetch next step's b0, b1 BEFORE the barrier (t-invariant addrs);
        // they stay in flight across it (raw barrier: no vmcnt drain).
        SISSUE(sA0, sA1, sA2, sA3, 0)
        SISSUE(sB0, sB1, sB2, sB3, 1)
        asm volatile("s_waitcnt lgkmcnt(0)\n\ts_barrier" ::: "memory");
        // global store after the barrier: fire-and-forget, no reader until
        // kernel end; never drained inside the loop.
        if (!sg) {
            feats[(size_t)(((b << 9) + t)) * 512 + (dir << 8) + (tid >> 1)] = h;
        }
        r0 = hpair[pp][lane];
        r1 = hpair[pp][64 + lane];
        pp ^= 1;
        g = gnext;
    }
}

// ---------------------------------------------------------------------------
// emis_kernel: emissions[b,t,k] = feats[b,t,:] . W_out[k,:] + b_out[k]
// ---------------------------------------------------------------------------
__global__ __launch_bounds__(64) void emis_kernel(const float* __restrict__ feats,
                                                  const float* __restrict__ Wout,
                                                  const float* __restrict__ bout,
                                                  const int* __restrict__ lens,
                                                  float* __restrict__ emis) {
    int r = blockIdx.x;
    int b = r >> 9, t = r & 511;
    if (t >= lens[b]) return;
    int lane = threadIdx.x;
    const float* fr = feats + (size_t)r * 512;
    float f[8];
#pragma unroll
    for (int i = 0; i < 8; ++i) f[i] = fr[i * 64 + lane];
#pragma unroll
    for (int k = 0; k < 9; ++k) {
        float p = 0.0f;
#pragma unroll
        for (int i = 0; i < 8; ++i) p = fmaf(f[i], Wout[k * 512 + i * 64 + lane], p);
#pragma unroll
        for (int off = 32; off; off >>= 1) p += __shfl_down(p, off);
        if (lane == 0) emis[r * 9 + k] = p + bout[k];
    }
}

// ---------------------------------------------------------------------------
// crf_kernel: alpha recursion + viterbi + backtrace + numerator + loss.
// ---------------------------------------------------------------------------
__global__ __launch_bounds__(64) void crf_kernel(const float* __restrict__ emis,
                                                 const int* __restrict__ lens,
                                                 const int* __restrict__ labels,
                                                 const float* __restrict__ start_trans,
                                                 const float* __restrict__ end_trans,
                                                 const float* __restrict__ trans,
                                                 float* __restrict__ out) {
    int b = blockIdx.x;
    int len = lens[b];
    int lane = threadIdx.x;
    __shared__ float alpha[9], vit[9];
    __shared__ unsigned char hist[512 * 9];
    const float* eb = emis + b * 512 * 9;
    const int* lb = labels + b * 512;

    float tr[9];
    if (lane < 9) {
#pragma unroll
        for (int i = 0; i < 9; ++i) tr[i] = trans[i * 9 + lane];
        float s0 = start_trans[lane] + eb[lane];
        alpha[lane] = s0;
        vit[lane] = s0;
    }
    __syncthreads();

    for (int t = 1; t < len; ++t) {
        float na = 0.0f, nv = 0.0f;
        if (lane < 9) {
            float e = eb[t * 9 + lane];
            float a[9];
#pragma unroll
            for (int i = 0; i < 9; ++i) a[i] = alpha[i] + tr[i];
            float m = a[0];
#pragma unroll
            for (int i = 1; i < 9; ++i) m = fmaxf(m, a[i]);
            float s = 0.0f;
#pragma unroll
            for (int i = 0; i < 9; ++i) s += __expf(a[i] - m);
            na = m + __logf(s) + e;
            float bv = vit[0] + tr[0];
            int bi = 0;
#pragma unroll
            for (int i = 1; i < 9; ++i) {
                float x = vit[i] + tr[i];
                if (x > bv) { bv = x; bi = i; }
            }
            nv = bv + e;
            hist[t * 9 + lane] = (unsigned char)bi;
        }
        __syncthreads();
        if (lane < 9) { alpha[lane] = na; vit[lane] = nv; }
        __syncthreads();
    }

    float part = 0.0f;
    for (int t = 1 + lane; t < len; t += 64) {
        int yp = lb[t - 1], y = lb[t];
        part += trans[yp * 9 + y] + eb[t * 9 + y];
    }
#pragma unroll
    for (int off = 32; off; off >>= 1) part += __shfl_down(part, off);

    if (lane == 0) {
        int y0 = lb[0];
        float num = start_trans[y0] + eb[y0] + part + end_trans[lb[len - 1]];
        float m = alpha[0] + end_trans[0];
        for (int j = 1; j < 9; ++j) m = fmaxf(m, alpha[j] + end_trans[j]);
        float s = 0.0f;
        for (int j = 0; j < 9; ++j) s += __expf(alpha[j] + end_trans[j] - m);
        float denom = m + __logf(s);
        atomicAdd(out, (denom - num) * (1.0f / 64.0f));

        float bm = vit[0] + end_trans[0];
        int cur = 0;
        for (int j = 1; j < 9; ++j) {
            float x = vit[j] + end_trans[j];
            if (x > bm) { bm = x; cur = j; }
        }
        float* preds = out + 1 + b * 512;
        preds[len - 1] = (float)cur;
        for (int t = len - 1; t >= 1; --t) {
            cur = hist[t * 9 + cur];
            preds[t - 1] = (float)cur;
        }
    }
}

// ---------------------------------------------------------------------------
extern "C" void kernel_launch(void* const* d_in, const int* in_sizes, int n_in,
                              void* d_out, int out_size, void* d_ws, size_t ws_size,
                              hipStream_t stream) {
    const int* widx = (const int*)d_in[0];
    const int* lens = (const int*)d_in[1];
    const int* labels = (const int*)d_in[2];
    const float* wvec = (const float*)d_in[3];
    const float* WihF = (const float*)d_in[4];
    const float* WhhF = (const float*)d_in[5];
    const float* bF = (const float*)d_in[6];
    const float* WihB = (const float*)d_in[7];
    const float* WhhB = (const float*)d_in[8];
    const float* bB = (const float*)d_in[9];
    const float* Wout = (const float*)d_in[10];
    const float* bout = (const float*)d_in[11];
    const float* start_trans = (const float*)d_in[12];
    const float* end_trans = (const float*)d_in[13];
    const float* trans9 = (const float*)d_in[14];
    float* out = (float*)d_out;
    char* ws = (char*)d_ws;

    // workspace layout (bytes)
    _Float16* gxF = (_Float16*)(ws);                        // 67,108,864
    _Float16* gxB = (_Float16*)(ws + 67108864);             // 67,108,864
    uint* wregF   = (uint*)(ws + 134217728);                // 106,496
    uint* wregB   = (uint*)(ws + 134324224);                // 106,496
    uint* wldsF   = (uint*)(ws + 134430720);                // 155,648
    uint* wldsB   = (uint*)(ws + 134586368);                // 155,648
    uint* wstrF   = (uint*)(ws + 134742016);                // 262,144
    uint* wstrB   = (uint*)(ws + 135004160);                // 262,144
    // wih16F/B live only before lstm; emis written after lstm -> safe alias
    uint* wih16F  = (uint*)(ws + 135266304);                // 524,288
    uint* wih16B  = (uint*)(ws + 135790592);                // 524,288
    float* emis   = (float*)(ws + 135266304);               // 1,179,648 (alias)
    (void)in_sizes; (void)n_in; (void)out_size; (void)ws_size;

    float* feats = out + 1 + 32768;   // feats output region (B,T,512) fp32

    zero_kernel<<<65665, 256, 0, stream>>>(out, lens);
    pack_kernel<<<1024, 256, 0, stream>>>(WhhF, WhhB, wregF, wregB, wldsF, wldsB,
                                          wstrF, wstrB);
    wih_pack_kernel<<<1024, 256, 0, stream>>>(WihF, WihB, wih16F, wih16B);

    dim3 ggrid(512, 16);
    gemm_gx_kernel<<<ggrid, 256, 0, stream>>>(widx, lens, wvec, wih16F, bF, gxF);
    gemm_gx_kernel<<<ggrid, 256, 0, stream>>>(widx, lens, wvec, wih16B, bB, gxB);

    lstm_kernel<<<128, 512, 0, stream>>>(gxF, gxB, wregF, wregB, wldsF, wldsB,
                                         wstrF, wstrB, lens, feats);

    emis_kernel<<<32768, 64, 0, stream>>>(feats, Wout, bout, lens, emis);
    crf_kernel<<<64, 64, 0, stream>>>(emis, lens, labels, start_trans, end_trans, trans9, out);
}

// Round 7
// 1605.678 us; speedup vs baseline: 1.3283x; 1.0098x over previous
//
#include <hip/hip_runtime.h>
#include <hip/hip_bf16.h>
#include <math.h>

#ifndef __has_builtin
#define __has_builtin(x) 0
#endif

typedef unsigned int uint;
typedef unsigned short ushort;
typedef _Float16 half2_t __attribute__((ext_vector_type(2)));

// Problem constants: B=64, T=512, V=30000, E=256, H=256, K=9. 4H = 1024.
//
// Round-6 lesson: step time ~4740 cyc == serial sum of VALU (1880) +
// L2-stream (~2330) + LDS (~456) — zero overlap. Cause: LDS rotation was
// only 2-3 ops deep (ds_read_b128 latency ~120 cyc -> ~100 cyc stall on
// ~17 of 19 LCONS = ~1700 cyc/step) and stream issue->consume ~120 cyc
// < L2 latency 200-400 cyc.
// THIS ROUND: 5-deep LDS rotation (LCONS(i) paired with LLOAD(i+5)) and
// WSTEP/stream phases interleaved BETWEEN LDS pairs. VGPR ledger:
// 52 W + 20 d + 32 landing + ~20 working ~= 124 <= cap-128 (the allocator's
// fixed budget for 512-thr blocks; every occupancy hint ignored, rounds 0-4).
#define WREG_UINTS (26 * 2 * 512)          // 26624
#define WLDS_U4    (19 * 512)              // 9728 uint4 = 155648 B
#define WSTR_U4    (32 * 512)              // 16384 uint4 = 262144 B

__device__ __forceinline__ float sigm(float x) {
    return __fdividef(1.0f, 1.0f + __expf(-x));
}
__device__ __forceinline__ float tanh_fast(float x) {
    float sg = __fdividef(1.0f, 1.0f + __expf(-2.0f * x));
    return sg + sg - 1.0f;
}
__device__ __forceinline__ float dot2f(uint w, uint h, float acc) {
#if __has_builtin(__builtin_amdgcn_fdot2)
    return __builtin_amdgcn_fdot2(__builtin_bit_cast(half2_t, w),
                                  __builtin_bit_cast(half2_t, h), acc, false);
#else
    half2_t a = __builtin_bit_cast(half2_t, w);
    half2_t b = __builtin_bit_cast(half2_t, h);
    return acc + (float)a.x * (float)b.x + (float)a.y * (float)b.y;
#endif
}
__device__ __forceinline__ uint packh2(float a, float b) {
    ushort u0 = __builtin_bit_cast(ushort, (_Float16)a);
    ushort u1 = __builtin_bit_cast(ushort, (_Float16)b);
    return (uint)u0 | ((uint)u1 << 16);
}

// ---- preprocessor repetition ------------------------------------------------
#define R26(X) \
  X(0) X(1) X(2) X(3) X(4) X(5) X(6) X(7) \
  X(8) X(9) X(10) X(11) X(12) X(13) X(14) X(15) \
  X(16) X(17) X(18) X(19) X(20) X(21) X(22) X(23) \
  X(24) X(25)

#define WDECL(m) uint wA##m, wB##m;
#define WLOAD(m) wA##m = wreg[(2 * (m)) * 512 + tid]; \
                 wB##m = wreg[(2 * (m) + 1) * 512 + tid];
#define WSTEP(m) { \
    uint hp = (uint)__builtin_amdgcn_readlane((int)r0, (m)); \
    aA = dot2f(wA##m, hp, aA); \
    aB = dot2f(wB##m, hp, aB); }

// LDS tier: group i (0..18) = pairs 26+2i, 27+2i (both r0 lanes).
#define LLOAD(dv, i) dv = lw4[(i) * 512 + tid];
#define LCONS(dv, i) { \
    uint hp0 = (uint)__builtin_amdgcn_readlane((int)r0, 26 + 2 * (i)); \
    uint hp1 = (uint)__builtin_amdgcn_readlane((int)r0, 27 + 2 * (i)); \
    aA = dot2f(dv.x, hp0, aA); \
    aB = dot2f(dv.y, hp0, aB); \
    aA = dot2f(dv.z, hp1, aA); \
    aB = dot2f(dv.w, hp1, aB); }

// Stream tier: uint4 group s (0..31) = pairs 64+2s, 65+2s (r1 lanes 2s, 2s+1)
#define SGRP(u, s) { \
    uint hp0 = (uint)__builtin_amdgcn_readlane((int)r1, 2 * (s)); \
    uint hp1 = (uint)__builtin_amdgcn_readlane((int)r1, 2 * (s) + 1); \
    aA = dot2f(u.x, hp0, aA); \
    aB = dot2f(u.y, hp0, aB); \
    aA = dot2f(u.z, hp1, aA); \
    aB = dot2f(u.w, hp1, aB); }
#define SISSUE(s0_, s1_, s2_, s3_, j) { \
    s0_ = wstr4[(4 * (j) + 0) * 512 + tid]; \
    s1_ = wstr4[(4 * (j) + 1) * 512 + tid]; \
    s2_ = wstr4[(4 * (j) + 2) * 512 + tid]; \
    s3_ = wstr4[(4 * (j) + 3) * 512 + tid]; }
#define SCONSB(s0_, s1_, s2_, s3_, j) \
    SGRP(s0_, 4 * (j) + 0) SGRP(s1_, 4 * (j) + 1) \
    SGRP(s2_, 4 * (j) + 2) SGRP(s3_, 4 * (j) + 3)

// ---------------------------------------------------------------------------
// zero_kernel: zero loss, preds, and feats rows with t >= len (masked region).
// ---------------------------------------------------------------------------
__global__ __launch_bounds__(256) void zero_kernel(float* __restrict__ out,
                                                   const int* __restrict__ lens) {
    int bid = blockIdx.x;
    if (bid < 65536) {
        int g = bid * 256 + threadIdx.x;
        int row = g >> 9;
        int t = row & 511;
        int b = row >> 9;
        if (t >= lens[b]) out[32769 + g] = 0.0f;
    } else if (bid < 65536 + 128) {
        int p = (bid - 65536) * 256 + threadIdx.x;
        out[1 + p] = 0.0f;
    } else if (threadIdx.x == 0) {
        out[0] = 0.0f;
    }
}

// ---------------------------------------------------------------------------
// pack_kernel: W_hh (4H,H) fp32 -> fp16 k-pair-packed, three destinations.
// Flat uint id per dir: m = id>>10 (k-pair 0..127), r = id&1023, x = r>>9
// (gate half), tl = r&511 (thread). Thread tl=2j+s owns gates q=2s+x of
// hidden j.
//   m<26        -> wreg[(2m+x)*512 + tl]
//   26<=m<64    -> mL=m-26: wlds[((mL>>1)*512 + tl)*4 + (mL&1)*2+x]
//   m>=64       -> mS=m-64: wstr[((mS>>1)*512 + tl)*4 + (mS&1)*2+x]
// grid = 1024 x 256 covers 2 dirs x 131072.
// ---------------------------------------------------------------------------
__global__ __launch_bounds__(256) void pack_kernel(const float* __restrict__ WF,
                                                   const float* __restrict__ WB,
                                                   uint* __restrict__ wregF,
                                                   uint* __restrict__ wregB,
                                                   uint* __restrict__ wldsF,
                                                   uint* __restrict__ wldsB,
                                                   uint* __restrict__ wstrF,
                                                   uint* __restrict__ wstrB) {
    int id = blockIdx.x * 256 + threadIdx.x;   // 0..262143
    const float* W = WF; uint* wr = wregF; uint* wl = wldsF; uint* wsp = wstrF;
    if (id >= 131072) { id -= 131072; W = WB; wr = wregB; wl = wldsB; wsp = wstrB; }
    int m = id >> 10;
    int r = id & 1023;
    int x = r >> 9;
    int tl = r & 511;
    int j = tl >> 1, s = tl & 1;
    int q = (s << 1) + x;
    const float* row = W + ((size_t)((q << 8) + j) << 8);
    uint pk = packh2(row[2 * m], row[2 * m + 1]);
    if (m < 26) {
        wr[((m << 1) + x) * 512 + tl] = pk;
    } else if (m < 64) {
        int mL = m - 26;
        wl[(((mL >> 1) << 9) + tl) * 4 + ((mL & 1) << 1) + x] = pk;
    } else {
        int mS = m - 64;
        wsp[(((mS >> 1) << 9) + tl) * 4 + ((mS & 1) << 1) + x] = pk;
    }
}

// ---------------------------------------------------------------------------
// wih_pack_kernel: Wih fp32 -> fp16 k-pair packed, indexed by interleaved
// output column: wih16[col*128 + p], perm(col) = (col&3)*256 + (col>>2).
// ---------------------------------------------------------------------------
__global__ __launch_bounds__(256) void wih_pack_kernel(const float* __restrict__ WihF,
                                                       const float* __restrict__ WihB,
                                                       uint* __restrict__ w16F,
                                                       uint* __restrict__ w16B) {
    int id = blockIdx.x * 256 + threadIdx.x;   // 0..262143
    const float* W = WihF; uint* dst = w16F;
    if (id >= 131072) { id -= 131072; W = WihB; dst = w16B; }
    int col = id >> 7;
    int p = id & 127;
    int perm = ((col & 3) << 8) + (col >> 2);
    const float* row = W + ((size_t)perm << 8);
    dst[(col << 7) + p] = packh2(row[2 * p], row[2 * p + 1]);
}

// ---------------------------------------------------------------------------
// gemm_gx: fp16-pair dot2 GEMM. gx_il[row][col] = emb[row].Wih[perm(col)] +
// bias[perm(col)]. 64x64 tile, 32 k per iter, 4x4/thread. Skips masked tiles.
// grid = (512, 16)
// ---------------------------------------------------------------------------
__global__ __launch_bounds__(256) void gemm_gx_kernel(const int* __restrict__ widx,
                                                      const int* __restrict__ lens,
                                                      const float* __restrict__ wvec,
                                                      const uint* __restrict__ wih16,
                                                      const float* __restrict__ bias,
                                                      _Float16* __restrict__ gx) {
    int row0 = blockIdx.x * 64;
    int b = row0 >> 9;
    int t0 = row0 & 511;
    if (t0 >= lens[b]) return;
    int n0 = blockIdx.y * 64;

    __shared__ __align__(16) uint As[16][68];
    __shared__ __align__(16) uint Bs[16][68];
    __shared__ int aoff[64];

    int tid = threadIdx.x;
    if (tid < 64) aoff[tid] = widx[row0 + tid] << 8;
    __syncthreads();

    float acc[4][4] = {};
    int tn = tid & 15, tm = tid >> 4;

    for (int k0p = 0; k0p < 128; k0p += 16) {
#pragma unroll
        for (int p = 0; p < 4; ++p) {
            int lin = p * 256 + tid;
            int kp = lin & 15, m = lin >> 4;
            const float2 av = *reinterpret_cast<const float2*>(
                &wvec[aoff[m] + ((k0p + kp) << 1)]);
            As[kp][m] = packh2(av.x, av.y);
            Bs[kp][m] = wih16[((n0 + m) << 7) + k0p + kp];
        }
        __syncthreads();
#pragma unroll
        for (int kp = 0; kp < 16; ++kp) {
            uint4 a4 = *reinterpret_cast<const uint4*>(&As[kp][tm * 4]);
            uint4 b4 = *reinterpret_cast<const uint4*>(&Bs[kp][tn * 4]);
            uint am[4] = {a4.x, a4.y, a4.z, a4.w};
            uint bn[4] = {b4.x, b4.y, b4.z, b4.w};
#pragma unroll
            for (int i = 0; i < 4; ++i)
#pragma unroll
                for (int j = 0; j < 4; ++j) acc[i][j] = dot2f(am[i], bn[j], acc[i][j]);
        }
        __syncthreads();
    }

#pragma unroll
    for (int i = 0; i < 4; ++i) {
        int row = row0 + tm * 4 + i;
        ushort u[4];
#pragma unroll
        for (int j = 0; j < 4; ++j) {
            int col = n0 + tn * 4 + j;
            int perm = ((col & 3) << 8) + (col >> 2);
            u[j] = __builtin_bit_cast(ushort, (_Float16)(acc[i][j] + bias[perm]));
        }
        uint2 st;
        st.x = (uint)u[0] | ((uint)u[1] << 16);
        st.y = (uint)u[2] | ((uint)u[3] << 16);
        *reinterpret_cast<uint2*>(&gx[row * 1024 + n0 + tn * 4]) = st;
    }
}

// ---------------------------------------------------------------------------
// lstm_kernel: one block per (b, dir); 512 threads. Thread 2j+s owns gate
// rows {2s, 2s+1} of hidden j. Three-tier W (26 reg / 38 LDS / 64 stream).
// 5-deep LDS rotation: LCONS(i) paired with LLOAD(i+5) -> every ds_read has
// >=5 independent ops (~100-150 cyc wall) before its consumer. WSTEP and
// stream phases interleaved between LDS pairs. Raw asm barrier (lgkmcnt
// only) keeps stream prefetch + feats store in flight across the step.
// ---------------------------------------------------------------------------
__global__ __launch_bounds__(512)
void lstm_kernel(const _Float16* __restrict__ gx0,
                 const _Float16* __restrict__ gx1,
                 const uint* __restrict__ wreg0,
                 const uint* __restrict__ wreg1,
                 const uint* __restrict__ wlds0,
                 const uint* __restrict__ wlds1,
                 const uint* __restrict__ wstr0,
                 const uint* __restrict__ wstr1,
                 const int* __restrict__ lens,
                 float* __restrict__ feats) {
    int dir = blockIdx.x & 1;
    int b = blockIdx.x >> 1;
    const uint* gxu = reinterpret_cast<const uint*>(dir ? gx1 : gx0) + ((size_t)(b << 9) << 9);
    const uint* wreg = dir ? wreg1 : wreg0;
    const uint4* wlds4 = reinterpret_cast<const uint4*>(dir ? wlds1 : wlds0);
    const uint4* wstr4 = reinterpret_cast<const uint4*>(dir ? wstr1 : wstr0);
    int len = lens[b];
    int tid = threadIdx.x;
    int lane = tid & 63;
    int sg = tid & 1;

    __shared__ __align__(16) uint4 lw4[WLDS_U4];     // 152 KB LDS W chunk
    __shared__ __align__(16) uint hpair[2][128];     // fp16-pair h, dbuf

    for (int i = tid; i < WLDS_U4; i += 512) lw4[i] = wlds4[i];

    R26(WDECL)            // uint wA0..wA25, wB0..wB25 — named scalars
    R26(WLOAD)
    __syncthreads();

    float c = 0.0f;
    uint r0 = 0, r1 = 0;
    int pp = 0;

    int t0i = dir ? (len - 1) : 0;
    uint g = gxu[(t0i << 9) + tid];

    uint4 sA0, sA1, sA2, sA3;      // stream landing set A
    uint4 sB0, sB1, sB2, sB3;      // stream landing set B
    uint4 d0, d1, d2, d3, d4;      // LDS pipeline regs (5-deep)

    // prologue: batches b0, b1 in flight into the loop
    SISSUE(sA0, sA1, sA2, sA3, 0)
    SISSUE(sB0, sB1, sB2, sB3, 1)

    for (int tp = 0; tp < len; ++tp) {
        int t = dir ? (len - 1 - tp) : tp;
        int tnn = dir ? (len - 2 - tp) : (tp + 1);
        tnn = tnn < 0 ? 0 : (tnn >= len ? len - 1 : tnn);
        uint gnext = gxu[(tnn << 9) + tid];

        half2_t gv = __builtin_bit_cast(half2_t, g);
        float aA = (float)gv.x;
        float aB = (float)gv.y;

        // fill LDS pipeline 5 deep
        LLOAD(d0, 0) LLOAD(d1, 1) LLOAD(d2, 2) LLOAD(d3, 3) LLOAD(d4, 4)
        WSTEP(0)  WSTEP(1)  WSTEP(2)  WSTEP(3)  WSTEP(4)  WSTEP(5)
        WSTEP(6)  WSTEP(7)
        SCONSB(sA0, sA1, sA2, sA3, 0)       // b0 (in flight since prev step)
        SISSUE(sA0, sA1, sA2, sA3, 2)       // b2
        WSTEP(8)  WSTEP(9)  WSTEP(10) WSTEP(11) WSTEP(12) WSTEP(13)
        WSTEP(14) WSTEP(15) WSTEP(16)
        LCONS(d0, 0)  LLOAD(d0, 5)
        LCONS(d1, 1)  LLOAD(d1, 6)
        LCONS(d2, 2)  LLOAD(d2, 7)
        SCONSB(sB0, sB1, sB2, sB3, 1)       // b1
        SISSUE(sB0, sB1, sB2, sB3, 3)       // b3
        WSTEP(17) WSTEP(18) WSTEP(19) WSTEP(20) WSTEP(21) WSTEP(22)
        WSTEP(23) WSTEP(24) WSTEP(25)
        LCONS(d3, 3)  LLOAD(d3, 8)
        LCONS(d4, 4)  LLOAD(d4, 9)
        LCONS(d0, 5)  LLOAD(d0, 10)
        SCONSB(sA0, sA1, sA2, sA3, 2)       // b2
        SISSUE(sA0, sA1, sA2, sA3, 4)       // b4
        LCONS(d1, 6)  LLOAD(d1, 11)
        LCONS(d2, 7)  LLOAD(d2, 12)
        LCONS(d3, 8)  LLOAD(d3, 13)
        SCONSB(sB0, sB1, sB2, sB3, 3)       // b3
        SISSUE(sB0, sB1, sB2, sB3, 5)       // b5
        LCONS(d4, 9)  LLOAD(d4, 14)
        LCONS(d0, 10) LLOAD(d0, 15)
        LCONS(d1, 11) LLOAD(d1, 16)
        SCONSB(sA0, sA1, sA2, sA3, 4)       // b4
        SISSUE(sA0, sA1, sA2, sA3, 6)       // b6
        LCONS(d2, 12) LLOAD(d2, 17)
        LCONS(d3, 13) LLOAD(d3, 18)
        LCONS(d4, 14)
        SCONSB(sB0, sB1, sB2, sB3, 5)       // b5
        SISSUE(sB0, sB1, sB2, sB3, 7)       // b7
        LCONS(d0, 15) LCONS(d1, 16)
        SCONSB(sA0, sA1, sA2, sA3, 6)       // b6
        LCONS(d2, 17) LCONS(d3, 18)
        SCONSB(sB0, sB1, sB2, sB3, 7)       // b7

        // s=0: pA=sigm(i), pB=sigm(f) ; s=1: pA=tanh(g), pB=sigm(o)
        float y = sg ? aA + aA : aA;
        float sgm = __fdividef(1.0f, 1.0f + __expf(-y));
        float pA = sg ? sgm + sgm - 1.0f : sgm;
        float pB = sigm(aB);

        float oA = __shfl_xor(pA, 1);
        float oB = __shfl_xor(pB, 1);
        float si = sg ? oA : pA;
        float sf = sg ? oB : pB;
        float tg = sg ? pA : oA;
        float so = sg ? pB : oB;

        c = sf * c + si * tg;
        float h = so * tanh_fast(c);

        if (!sg) {
            reinterpret_cast<ushort*>(hpair[pp])[tid >> 1] =
                __builtin_bit_cast(ushort, (_Float16)h);
        }
        // prefetch next step's b0, b1 BEFORE the barrier (t-invariant addrs);
        // they stay in flight across it (raw barrier: no vmcnt drain).
        SISSUE(sA0, sA1, sA2, sA3, 0)
        SISSUE(sB0, sB1, sB2, sB3, 1)
        asm volatile("s_waitcnt lgkmcnt(0)\n\ts_barrier" ::: "memory");
        // global store after the barrier: fire-and-forget, no reader until
        // kernel end; never drained inside the loop.
        if (!sg) {
            feats[(size_t)(((b << 9) + t)) * 512 + (dir << 8) + (tid >> 1)] = h;
        }
        r0 = hpair[pp][lane];
        r1 = hpair[pp][64 + lane];
        pp ^= 1;
        g = gnext;
    }
}

// ---------------------------------------------------------------------------
// emis_kernel: emissions[b,t,k] = feats[b,t,:] . W_out[k,:] + b_out[k]
// ---------------------------------------------------------------------------
__global__ __launch_bounds__(64) void emis_kernel(const float* __restrict__ feats,
                                                  const float* __restrict__ Wout,
                                                  const float* __restrict__ bout,
                                                  const int* __restrict__ lens,
                                                  float* __restrict__ emis) {
    int r = blockIdx.x;
    int b = r >> 9, t = r & 511;
    if (t >= lens[b]) return;
    int lane = threadIdx.x;
    const float* fr = feats + (size_t)r * 512;
    float f[8];
#pragma unroll
    for (int i = 0; i < 8; ++i) f[i] = fr[i * 64 + lane];
#pragma unroll
    for (int k = 0; k < 9; ++k) {
        float p = 0.0f;
#pragma unroll
        for (int i = 0; i < 8; ++i) p = fmaf(f[i], Wout[k * 512 + i * 64 + lane], p);
#pragma unroll
        for (int off = 32; off; off >>= 1) p += __shfl_down(p, off);
        if (lane == 0) emis[r * 9 + k] = p + bout[k];
    }
}

// ---------------------------------------------------------------------------
// crf_kernel: alpha recursion + viterbi + backtrace + numerator + loss.
// ---------------------------------------------------------------------------
__global__ __launch_bounds__(64) void crf_kernel(const float* __restrict__ emis,
                                                 const int* __restrict__ lens,
                                                 const int* __restrict__ labels,
                                                 const float* __restrict__ start_trans,
                                                 const float* __restrict__ end_trans,
                                                 const float* __restrict__ trans,
                                                 float* __restrict__ out) {
    int b = blockIdx.x;
    int len = lens[b];
    int lane = threadIdx.x;
    __shared__ float alpha[9], vit[9];
    __shared__ unsigned char hist[512 * 9];
    const float* eb = emis + b * 512 * 9;
    const int* lb = labels + b * 512;

    float tr[9];
    if (lane < 9) {
#pragma unroll
        for (int i = 0; i < 9; ++i) tr[i] = trans[i * 9 + lane];
        float s0 = start_trans[lane] + eb[lane];
        alpha[lane] = s0;
        vit[lane] = s0;
    }
    __syncthreads();

    for (int t = 1; t < len; ++t) {
        float na = 0.0f, nv = 0.0f;
        if (lane < 9) {
            float e = eb[t * 9 + lane];
            float a[9];
#pragma unroll
            for (int i = 0; i < 9; ++i) a[i] = alpha[i] + tr[i];
            float m = a[0];
#pragma unroll
            for (int i = 1; i < 9; ++i) m = fmaxf(m, a[i]);
            float s = 0.0f;
#pragma unroll
            for (int i = 0; i < 9; ++i) s += __expf(a[i] - m);
            na = m + __logf(s) + e;
            float bv = vit[0] + tr[0];
            int bi = 0;
#pragma unroll
            for (int i = 1; i < 9; ++i) {
                float x = vit[i] + tr[i];
                if (x > bv) { bv = x; bi = i; }
            }
            nv = bv + e;
            hist[t * 9 + lane] = (unsigned char)bi;
        }
        __syncthreads();
        if (lane < 9) { alpha[lane] = na; vit[lane] = nv; }
        __syncthreads();
    }

    float part = 0.0f;
    for (int t = 1 + lane; t < len; t += 64) {
        int yp = lb[t - 1], y = lb[t];
        part += trans[yp * 9 + y] + eb[t * 9 + y];
    }
#pragma unroll
    for (int off = 32; off; off >>= 1) part += __shfl_down(part, off);

    if (lane == 0) {
        int y0 = lb[0];
        float num = start_trans[y0] + eb[y0] + part + end_trans[lb[len - 1]];
        float m = alpha[0] + end_trans[0];
        for (int j = 1; j < 9; ++j) m = fmaxf(m, alpha[j] + end_trans[j]);
        float s = 0.0f;
        for (int j = 0; j < 9; ++j) s += __expf(alpha[j] + end_trans[j] - m);
        float denom = m + __logf(s);
        atomicAdd(out, (denom - num) * (1.0f / 64.0f));

        float bm = vit[0] + end_trans[0];
        int cur = 0;
        for (int j = 1; j < 9; ++j) {
            float x = vit[j] + end_trans[j];
            if (x > bm) { bm = x; cur = j; }
        }
        float* preds = out + 1 + b * 512;
        preds[len - 1] = (float)cur;
        for (int t = len - 1; t >= 1; --t) {
            cur = hist[t * 9 + cur];
            preds[t - 1] = (float)cur;
        }
    }
}

// ---------------------------------------------------------------------------
extern "C" void kernel_launch(void* const* d_in, const int* in_sizes, int n_in,
                              void* d_out, int out_size, void* d_ws, size_t ws_size,
                              hipStream_t stream) {
    const int* widx = (const int*)d_in[0];
    const int* lens = (const int*)d_in[1];
    const int* labels = (const int*)d_in[2];
    const float* wvec = (const float*)d_in[3];
    const float* WihF = (const float*)d_in[4];
    const float* WhhF = (const float*)d_in[5];
    const float* bF = (const float*)d_in[6];
    const float* WihB = (const float*)d_in[7];
    const float* WhhB = (const float*)d_in[8];
    const float* bB = (const float*)d_in[9];
    const float* Wout = (const float*)d_in[10];
    const float* bout = (const float*)d_in[11];
    const float* start_trans = (const float*)d_in[12];
    const float* end_trans = (const float*)d_in[13];
    const float* trans9 = (const float*)d_in[14];
    float* out = (float*)d_out;
    char* ws = (char*)d_ws;

    // workspace layout (bytes)
    _Float16* gxF = (_Float16*)(ws);                        // 67,108,864
    _Float16* gxB = (_Float16*)(ws + 67108864);             // 67,108,864
    uint* wregF   = (uint*)(ws + 134217728);                // 106,496
    uint* wregB   = (uint*)(ws + 134324224);                // 106,496
    uint* wldsF   = (uint*)(ws + 134430720);                // 155,648
    uint* wldsB   = (uint*)(ws + 134586368);                // 155,648
    uint* wstrF   = (uint*)(ws + 134742016);                // 262,144
    uint* wstrB   = (uint*)(ws + 135004160);                // 262,144
    // wih16F/B live only before lstm; emis written after lstm -> safe alias
    uint* wih16F  = (uint*)(ws + 135266304);                // 524,288
    uint* wih16B  = (uint*)(ws + 135790592);                // 524,288
    float* emis   = (float*)(ws + 135266304);               // 1,179,648 (alias)
    (void)in_sizes; (void)n_in; (void)out_size; (void)ws_size;

    float* feats = out + 1 + 32768;   // feats output region (B,T,512) fp32

    zero_kernel<<<65665, 256, 0, stream>>>(out, lens);
    pack_kernel<<<1024, 256, 0, stream>>>(WhhF, WhhB, wregF, wregB, wldsF, wldsB,
                                          wstrF, wstrB);
    wih_pack_kernel<<<1024, 256, 0, stream>>>(WihF, WihB, wih16F, wih16B);

    dim3 ggrid(512, 16);
    gemm_gx_kernel<<<ggrid, 256, 0, stream>>>(widx, lens, wvec, wih16F, bF, gxF);
    gemm_gx_kernel<<<ggrid, 256, 0, stream>>>(widx, lens, wvec, wih16B, bB, gxB);

    lstm_kernel<<<128, 512, 0, stream>>>(gxF, gxB, wregF, wregB, wldsF, wldsB,
                                         wstrF, wstrB, lens, feats);

    emis_kernel<<<32768, 64, 0, stream>>>(feats, Wout, bout, lens, emis);
    crf_kernel<<<64, 64, 0, stream>>>(emis, lens, labels, start_trans, end_trans, trans9, out);
}